// Round 7
// baseline (842.647 us; speedup 1.0000x reference)
//
#include <hip/hip_runtime.h>
#include <cstdint>
#include <cstddef>

#define WAVE 64
#define NPB 4   // waves per aggregation block

#define TBM 128
#define TBN 128
#define TBK 32
#define LDK 40

typedef short s16x8 __attribute__((ext_vector_type(8)));
typedef float f32x4 __attribute__((ext_vector_type(4)));

__device__ __forceinline__ unsigned short f2bf(float f) {
    unsigned int u = __float_as_uint(f);
    unsigned int r = (u + 0x7fffu + ((u >> 16) & 1u)) >> 16;
    return (unsigned short)r;
}
__device__ __forceinline__ float bf2f_lo(unsigned int v) { return __uint_as_float(v << 16); }
__device__ __forceinline__ float bf2f_hi(unsigned int v) { return __uint_as_float(v & 0xffff0000u); }
__device__ __forceinline__ float lrelu02(float e) { return (e > 0.f) ? e : 0.2f * e; }

// ==================== GEMM body ====================
// bias!=null => add bias + optional relu on cols < M (new-style layers).
// zpadTo > 0 => write 0 to cols in [M, zpadTo) (pad next activation buffer).
// asb!=null  => cols [M, M+2H) are alpha logits (old-style layers).

__device__ __forceinline__ void gemm_body(const unsigned short* __restrict__ A,
                                          const unsigned short* __restrict__ BT,
                                          unsigned short* __restrict__ Cbf,
                                          float* __restrict__ asb, float* __restrict__ adb,
                                          const float* __restrict__ bias, int relu, int zpadTo,
                                          int N, int Kp, int M, int Mext, int Mp, int H,
                                          int bx, int by) {
    __shared__ __align__(16) unsigned short As[TBM * LDK];
    __shared__ __align__(16) unsigned short Bs[TBN * LDK];
    int tid = threadIdx.x;
    int wave = tid >> 6;
    int lane = tid & 63;
    int rowBase = by * TBM;
    int colBase = bx * TBN;
    int wm = (wave & 1) * 64;
    int wn = (wave >> 1) * 64;
    int l15 = lane & 15;
    int quad = lane >> 4;

    f32x4 acc[4][4];
    f32x4 z4 = {0.f, 0.f, 0.f, 0.f};
#pragma unroll
    for (int i = 0; i < 4; i++)
#pragma unroll
        for (int j = 0; j < 4; j++) acc[i][j] = z4;

    int srow = tid >> 2;
    int skg = tid & 3;
    const uint4 zero16 = {0u, 0u, 0u, 0u};

    for (int k0 = 0; k0 < Kp; k0 += TBK) {
#pragma unroll
        for (int half = 0; half < 2; half++) {
            int row = srow + half * 64;
            int gk = k0 + skg * 8;
            bool kok = (gk < Kp);
            {
                int gr = rowBase + row;
                uint4 v = zero16;
                if (kok && gr < N) v = *(const uint4*)(A + (size_t)gr * Kp + gk);
                *(uint4*)(As + row * LDK + skg * 8) = v;
            }
            {
                int gc = colBase + row;
                uint4 v = zero16;
                if (kok && gc < Mext) v = *(const uint4*)(BT + (size_t)gc * Kp + gk);
                *(uint4*)(Bs + row * LDK + skg * 8) = v;
            }
        }
        __syncthreads();

        s16x8 af[4], bfr[4];
#pragma unroll
        for (int mt = 0; mt < 4; mt++)
            af[mt] = *(const s16x8*)(As + (wm + mt * 16 + l15) * LDK + quad * 8);
#pragma unroll
        for (int nt = 0; nt < 4; nt++)
            bfr[nt] = *(const s16x8*)(Bs + (wn + nt * 16 + l15) * LDK + quad * 8);
#pragma unroll
        for (int mt = 0; mt < 4; mt++)
#pragma unroll
            for (int nt = 0; nt < 4; nt++)
                acc[mt][nt] = __builtin_amdgcn_mfma_f32_16x16x32_bf16(af[mt], bfr[nt], acc[mt][nt], 0, 0, 0);
        __syncthreads();
    }

#pragma unroll
    for (int mt = 0; mt < 4; mt++) {
#pragma unroll
        for (int r = 0; r < 4; r++) {
            int row = rowBase + wm + mt * 16 + quad * 4 + r;
            if (row < N) {
#pragma unroll
                for (int nt = 0; nt < 4; nt++) {
                    int col = colBase + wn + nt * 16 + l15;
                    float v = acc[mt][nt][r];
                    if (col < M) {
                        float v2 = v;
                        if (bias != nullptr) {
                            v2 += bias[col];
                            if (relu) v2 = fmaxf(v2, 0.f);
                        }
                        Cbf[(size_t)row * Mp + col] = f2bf(v2);
                    } else if (col < zpadTo) {
                        Cbf[(size_t)row * Mp + col] = 0;
                    } else if (asb != nullptr && col < M + 2 * H) {
                        int t = col - M;
                        if (t < H) asb[(size_t)row * H + t] = v;
                        else adb[(size_t)row * H + (t - H)] = v;
                    }
                }
            }
        }
    }
}

// ==================== old-style aggregation body ====================
// NEXTA: epilogue computes next layer's alpha logits as/ad = out . vanf (in-wave reduce).

template <int SLOTS, int G, int H, bool SM, int SWEEPS, bool GCN, bool NEXTA>
__device__ __forceinline__ void agg_body(const unsigned short* __restrict__ hfeat,
                                         const float* __restrict__ as_, const float* __restrict__ ad_,
                                         const float* __restrict__ dinv,
                                         const int* __restrict__ rowp, const int2* __restrict__ cpack,
                                         const float* __restrict__ bias,
                                         float* __restrict__ out_f, unsigned short* __restrict__ out_bf,
                                         const float* __restrict__ vanf, int vald,
                                         float* __restrict__ asn, float* __restrict__ adn_o,
                                         int HC, int ldo, int relu, int n, int lane) {
    constexpr int ROWB = SWEEPS * SLOTS * 16;
    int g = lane / SLOTS;
    int slot = lane - g * SLOTS;
    bool act = (g < G);
    int C = HC / H;
    int beg = rowp[n], end = rowp[n + 1];

    float adn[H], msub[H];
    float di = 0.f;
    if (GCN) {
        di = dinv[n];
    } else {
#pragma unroll
        for (int h = 0; h < H; h++) {
            adn[h] = ad_[(size_t)n * H + h];
            msub[h] = lrelu02(as_[(size_t)n * H + h] + adn[h]);
        }
    }

    int ch0[SWEEPS];
    bool h1q[SWEEPS][4];
#pragma unroll
    for (int sw = 0; sw < SWEEPS; sw++) {
        ch0[sw] = (sw * SLOTS + slot) * 8;
#pragma unroll
        for (int q = 0; q < 4; q++) h1q[sw][q] = (H == 2) && ((ch0[sw] + 2 * q) >= C);
    }

    float sfw = GCN ? di * di : 1.f;
    float accx[SWEEPS][4], accy[SWEEPS][4];
#pragma unroll
    for (int sw = 0; sw < SWEEPS; sw++)
#pragma unroll
        for (int q = 0; q < 4; q++) { accx[sw][q] = 0.f; accy[sw][q] = 0.f; }
    if (act && g == 0) {
#pragma unroll
        for (int sw = 0; sw < SWEEPS; sw++) {
            uint4 v = *(const uint4*)((const char*)hfeat + (size_t)n * ROWB + (sw * SLOTS + slot) * 16);
            unsigned int vv[4] = {v.x, v.y, v.z, v.w};
#pragma unroll
            for (int q = 0; q < 4; q++) { accx[sw][q] = sfw * bf2f_lo(vv[q]); accy[sw][q] = sfw * bf2f_hi(vv[q]); }
        }
    }

    float wsum[H];
#pragma unroll
    for (int h = 0; h < H; h++) wsum[h] = 0.f;

    for (int base = beg; base < end; base += WAVE) {
        int cnt = end - base;
        if (cnt > WAVE) cnt = WAVE;
        int s_l = 0;
        float w_l[H];
#pragma unroll
        for (int h = 0; h < H; h++) w_l[h] = 0.f;
        if (lane < cnt) {
            int2 pk = cpack[base + lane];
            s_l = pk.x;
            if (GCN) {
                w_l[0] = dinv[s_l] * __int_as_float(pk.y) * di;
            } else {
#pragma unroll
                for (int h = 0; h < H; h++)
                    w_l[h] = __expf(lrelu02(as_[(size_t)s_l * H + h] + adn[h]) - msub[h]);
            }
            if (SM) {
#pragma unroll
                for (int h = 0; h < H; h++) wsum[h] += w_l[h];
            }
        }
        for (int j0 = 0; j0 < cnt; j0 += 2 * G) {
            int sA;
            float wA[H];
            uint4 vA[SWEEPS];
            {
                int jj = j0 + g;
                bool pad = (jj >= cnt);
                if (jj > cnt - 1) jj = cnt - 1;
                int ba = jj << 2;
                sA = __builtin_amdgcn_ds_bpermute(ba, s_l);
#pragma unroll
                for (int h = 0; h < H; h++) {
                    float t = __uint_as_float(
                        (unsigned)__builtin_amdgcn_ds_bpermute(ba, (int)__float_as_uint(w_l[h])));
                    wA[h] = pad ? 0.f : t;
                }
                if (act) {
#pragma unroll
                    for (int sw = 0; sw < SWEEPS; sw++) {
                        unsigned voff = (unsigned)sA * ROWB + (sw * SLOTS + slot) * 16;
                        vA[sw] = *(const uint4*)((const char*)hfeat + voff);
                    }
                }
            }
            bool haveB = (j0 + G < cnt);
            int sB;
            float wB[H];
            uint4 vB[SWEEPS];
            if (haveB) {
                int jj = j0 + G + g;
                bool pad = (jj >= cnt);
                if (jj > cnt - 1) jj = cnt - 1;
                int ba = jj << 2;
                sB = __builtin_amdgcn_ds_bpermute(ba, s_l);
#pragma unroll
                for (int h = 0; h < H; h++) {
                    float t = __uint_as_float(
                        (unsigned)__builtin_amdgcn_ds_bpermute(ba, (int)__float_as_uint(w_l[h])));
                    wB[h] = pad ? 0.f : t;
                }
                if (act) {
#pragma unroll
                    for (int sw = 0; sw < SWEEPS; sw++) {
                        unsigned voff = (unsigned)sB * ROWB + (sw * SLOTS + slot) * 16;
                        vB[sw] = *(const uint4*)((const char*)hfeat + voff);
                    }
                }
            }
            if (act) {
#pragma unroll
                for (int sw = 0; sw < SWEEPS; sw++) {
                    unsigned int va[4] = {vA[sw].x, vA[sw].y, vA[sw].z, vA[sw].w};
#pragma unroll
                    for (int q = 0; q < 4; q++) {
                        float wq = (H == 2) ? (h1q[sw][q] ? wA[1] : wA[0]) : wA[0];
                        accx[sw][q] += wq * bf2f_lo(va[q]);
                        accy[sw][q] += wq * bf2f_hi(va[q]);
                    }
                }
                if (haveB) {
#pragma unroll
                    for (int sw = 0; sw < SWEEPS; sw++) {
                        unsigned int ub[4] = {vB[sw].x, vB[sw].y, vB[sw].z, vB[sw].w};
#pragma unroll
                        for (int q = 0; q < 4; q++) {
                            float wq = (H == 2) ? (h1q[sw][q] ? wB[1] : wB[0]) : wB[0];
                            accx[sw][q] += wq * bf2f_lo(ub[q]);
                            accy[sw][q] += wq * bf2f_hi(ub[q]);
                        }
                    }
                }
            }
        }
    }

    if (G == 3) {
#pragma unroll
        for (int sw = 0; sw < SWEEPS; sw++)
#pragma unroll
            for (int q = 0; q < 4; q++) {
                int b1a = (lane + SLOTS) << 2, b2a = (lane + 2 * SLOTS) << 2;
                float t1 = __uint_as_float((unsigned)__builtin_amdgcn_ds_bpermute(b1a, (int)__float_as_uint(accx[sw][q])));
                float t2 = __uint_as_float((unsigned)__builtin_amdgcn_ds_bpermute(b2a, (int)__float_as_uint(accx[sw][q])));
                accx[sw][q] += t1 + t2;
                float t3 = __uint_as_float((unsigned)__builtin_amdgcn_ds_bpermute(b1a, (int)__float_as_uint(accy[sw][q])));
                float t4 = __uint_as_float((unsigned)__builtin_amdgcn_ds_bpermute(b2a, (int)__float_as_uint(accy[sw][q])));
                accy[sw][q] += t3 + t4;
            }
    } else if (G == 8) {
#pragma unroll
        for (int st = 4; st >= 1; st >>= 1) {
            int ba = (lane + st * SLOTS) << 2;
#pragma unroll
            for (int sw = 0; sw < SWEEPS; sw++)
#pragma unroll
                for (int q = 0; q < 4; q++) {
                    accx[sw][q] += __uint_as_float((unsigned)__builtin_amdgcn_ds_bpermute(ba, (int)__float_as_uint(accx[sw][q])));
                    accy[sw][q] += __uint_as_float((unsigned)__builtin_amdgcn_ds_bpermute(ba, (int)__float_as_uint(accy[sw][q])));
                }
        }
    }

    float rs[H];
    if (SM) {
#pragma unroll
        for (int h = 0; h < H; h++) {
            float t = wsum[h];
            for (int off = 32; off > 0; off >>= 1) t += __shfl_xor(t, off);
            rs[h] = 1.f / (1.f + t + 1e-16f);
        }
    } else {
#pragma unroll
        for (int h = 0; h < H; h++) rs[h] = 1.f;
    }

    float ps[4] = {0.f, 0.f, 0.f, 0.f};
    if (lane < SLOTS) {
#pragma unroll
        for (int sw = 0; sw < SWEEPS; sw++) {
            float o[8];
#pragma unroll
            for (int q = 0; q < 4; q++) {
                float r = (H == 2) ? (h1q[sw][q] ? rs[1] : rs[0]) : rs[0];
                int c0 = ch0[sw] + 2 * q;
                float b0 = (c0 < HC) ? bias[c0] : 0.f;
                float b1v = (c0 + 1 < HC) ? bias[c0 + 1] : 0.f;
                float o0 = accx[sw][q] * r + b0;
                float o1 = accy[sw][q] * r + b1v;
                if (relu) { o0 = fmaxf(o0, 0.f); o1 = fmaxf(o1, 0.f); }
                if (c0 >= HC) o0 = 0.f;
                if (c0 + 1 >= HC) o1 = 0.f;
                o[2 * q] = o0;
                o[2 * q + 1] = o1;
            }
            if (NEXTA) {
#pragma unroll
                for (int j = 0; j < 8; j++) {
                    int c = ch0[sw] + j;
#pragma unroll
                    for (int th = 0; th < 4; th++) ps[th] += o[j] * vanf[th * vald + c];
                }
            }
            if (out_bf) {
                uint4 pk;
                unsigned* pp = (unsigned*)&pk;
#pragma unroll
                for (int q = 0; q < 4; q++)
                    pp[q] = (unsigned)f2bf(o[2 * q]) | ((unsigned)f2bf(o[2 * q + 1]) << 16);
                *(uint4*)((char*)out_bf + (size_t)n * ((size_t)ldo * 2) + (sw * SLOTS + slot) * 16) = pk;
            } else {
#pragma unroll
                for (int half = 0; half < 2; half++) {
                    int c0 = ch0[sw] + half * 4;
                    if (c0 < HC) {
                        float4 f4 = make_float4(o[half * 4], o[half * 4 + 1], o[half * 4 + 2], o[half * 4 + 3]);
                        *(float4*)(out_f + (size_t)n * HC + c0) = f4;
                    }
                }
            }
        }
    }
    if (NEXTA) {
#pragma unroll
        for (int th = 0; th < 4; th++)
            for (int off = 32; off > 0; off >>= 1) ps[th] += __shfl_xor(ps[th], off);
        if (lane == 0) {
            asn[(size_t)n * 2 + 0] = ps[0];
            asn[(size_t)n * 2 + 1] = ps[1];
            adn_o[(size_t)n * 2 + 0] = ps[2];
            adn_o[(size_t)n * 2 + 1] = ps[3];
        }
    }
}

// ==================== new-style (input-space) aggregation body ====================
// Gathers INPUT features x, accumulates per-head weighted sums, writes block-diag A2
// [N][2][SLOTS*8] bf16 (no bias/relu; softmax rs applied). H=2 fixed.

template <int SLOTS, int G>
__device__ __forceinline__ void aggN_body(const unsigned short* __restrict__ x,
                                          const float* __restrict__ as_, const float* __restrict__ ad_,
                                          const int* __restrict__ rowp, const int2* __restrict__ cpack,
                                          unsigned short* __restrict__ A2, int n, int lane) {
    constexpr int ROWB = SLOTS * 16;
    int g = lane / SLOTS;
    int slot = lane - g * SLOTS;
    bool act = (g < G);
    int beg = rowp[n], end = rowp[n + 1];

    float adn[2], msub[2];
#pragma unroll
    for (int h = 0; h < 2; h++) {
        adn[h] = ad_[(size_t)n * 2 + h];
        msub[h] = lrelu02(as_[(size_t)n * 2 + h] + adn[h]);
    }

    float ax[2][4], ay[2][4];
#pragma unroll
    for (int h = 0; h < 2; h++)
#pragma unroll
        for (int q = 0; q < 4; q++) { ax[h][q] = 0.f; ay[h][q] = 0.f; }
    if (act && g == 0) {
        uint4 v = *(const uint4*)((const char*)x + (size_t)n * ROWB + slot * 16);
        unsigned int vv[4] = {v.x, v.y, v.z, v.w};
#pragma unroll
        for (int q = 0; q < 4; q++) {
            float lo = bf2f_lo(vv[q]), hi = bf2f_hi(vv[q]);
            ax[0][q] = lo; ax[1][q] = lo;
            ay[0][q] = hi; ay[1][q] = hi;
        }
    }

    float wsum[2] = {0.f, 0.f};

    for (int base = beg; base < end; base += WAVE) {
        int cnt = end - base;
        if (cnt > WAVE) cnt = WAVE;
        int s_l = 0;
        float w_l[2] = {0.f, 0.f};
        if (lane < cnt) {
            s_l = cpack[base + lane].x;
#pragma unroll
            for (int h = 0; h < 2; h++)
                w_l[h] = __expf(lrelu02(as_[(size_t)s_l * 2 + h] + adn[h]) - msub[h]);
            wsum[0] += w_l[0];
            wsum[1] += w_l[1];
        }
        for (int j0 = 0; j0 < cnt; j0 += 2 * G) {
            int sA;
            float wA[2];
            uint4 vA;
            {
                int jj = j0 + g;
                bool pad = (jj >= cnt);
                if (jj > cnt - 1) jj = cnt - 1;
                int ba = jj << 2;
                sA = __builtin_amdgcn_ds_bpermute(ba, s_l);
#pragma unroll
                for (int h = 0; h < 2; h++) {
                    float t = __uint_as_float(
                        (unsigned)__builtin_amdgcn_ds_bpermute(ba, (int)__float_as_uint(w_l[h])));
                    wA[h] = pad ? 0.f : t;
                }
                if (act) vA = *(const uint4*)((const char*)x + (unsigned)sA * ROWB + slot * 16);
            }
            bool haveB = (j0 + G < cnt);
            int sB;
            float wB[2];
            uint4 vB;
            if (haveB) {
                int jj = j0 + G + g;
                bool pad = (jj >= cnt);
                if (jj > cnt - 1) jj = cnt - 1;
                int ba = jj << 2;
                sB = __builtin_amdgcn_ds_bpermute(ba, s_l);
#pragma unroll
                for (int h = 0; h < 2; h++) {
                    float t = __uint_as_float(
                        (unsigned)__builtin_amdgcn_ds_bpermute(ba, (int)__float_as_uint(w_l[h])));
                    wB[h] = pad ? 0.f : t;
                }
                if (act) vB = *(const uint4*)((const char*)x + (unsigned)sB * ROWB + slot * 16);
            }
            if (act) {
                unsigned int va[4] = {vA.x, vA.y, vA.z, vA.w};
#pragma unroll
                for (int q = 0; q < 4; q++) {
                    float lo = bf2f_lo(va[q]), hi = bf2f_hi(va[q]);
                    ax[0][q] += wA[0] * lo; ax[1][q] += wA[1] * lo;
                    ay[0][q] += wA[0] * hi; ay[1][q] += wA[1] * hi;
                }
                if (haveB) {
                    unsigned int ub[4] = {vB.x, vB.y, vB.z, vB.w};
#pragma unroll
                    for (int q = 0; q < 4; q++) {
                        float lo = bf2f_lo(ub[q]), hi = bf2f_hi(ub[q]);
                        ax[0][q] += wB[0] * lo; ax[1][q] += wB[1] * lo;
                        ay[0][q] += wB[0] * hi; ay[1][q] += wB[1] * hi;
                    }
                }
            }
        }
    }

    if (G == 3) {
#pragma unroll
        for (int h = 0; h < 2; h++)
#pragma unroll
            for (int q = 0; q < 4; q++) {
                int b1a = (lane + SLOTS) << 2, b2a = (lane + 2 * SLOTS) << 2;
                float t1 = __uint_as_float((unsigned)__builtin_amdgcn_ds_bpermute(b1a, (int)__float_as_uint(ax[h][q])));
                float t2 = __uint_as_float((unsigned)__builtin_amdgcn_ds_bpermute(b2a, (int)__float_as_uint(ax[h][q])));
                ax[h][q] += t1 + t2;
                float t3 = __uint_as_float((unsigned)__builtin_amdgcn_ds_bpermute(b1a, (int)__float_as_uint(ay[h][q])));
                float t4 = __uint_as_float((unsigned)__builtin_amdgcn_ds_bpermute(b2a, (int)__float_as_uint(ay[h][q])));
                ay[h][q] += t3 + t4;
            }
    } else if (G == 8) {
#pragma unroll
        for (int st = 4; st >= 1; st >>= 1) {
            int ba = (lane + st * SLOTS) << 2;
#pragma unroll
            for (int h = 0; h < 2; h++)
#pragma unroll
                for (int q = 0; q < 4; q++) {
                    ax[h][q] += __uint_as_float((unsigned)__builtin_amdgcn_ds_bpermute(ba, (int)__float_as_uint(ax[h][q])));
                    ay[h][q] += __uint_as_float((unsigned)__builtin_amdgcn_ds_bpermute(ba, (int)__float_as_uint(ay[h][q])));
                }
        }
    }

    float rs[2];
#pragma unroll
    for (int h = 0; h < 2; h++) {
        float t = wsum[h];
        for (int off = 32; off > 0; off >>= 1) t += __shfl_xor(t, off);
        rs[h] = 1.f / (1.f + t + 1e-16f);
    }

    if (lane < SLOTS) {
#pragma unroll
        for (int h = 0; h < 2; h++) {
            uint4 pk;
            unsigned* pp = (unsigned*)&pk;
#pragma unroll
            for (int q = 0; q < 4; q++) {
                float o0 = ax[h][q] * rs[h];
                float o1 = ay[h][q] * rs[h];
                pp[q] = (unsigned)f2bf(o0) | ((unsigned)f2bf(o1) << 16);
            }
            *(uint4*)((char*)A2 + (size_t)n * (2 * ROWB) + h * ROWB + slot * 16) = pk;
        }
    }
}

// ==================== helpers for kernel A ====================

__device__ __forceinline__ void cvtw1(const float* __restrict__ W, unsigned short* __restrict__ WT,
                                      int K, int M, int Kp, int i) {
    int m = i / Kp;
    int k = i - m * Kp;
    WT[i] = (k < K) ? f2bf(W[(long long)k * M + m]) : (unsigned short)0;
}

// block-diag builders: row m (out col), head band at [h*Kph, h*Kph+K)
__device__ __forceinline__ void cvtw_bd(const float* __restrict__ W, unsigned short* __restrict__ WT,
                                        int K, int M, int C, int Kp, int Kph, int i) {
    int m = i / Kp;
    int k = i - m * Kp;
    unsigned short v = 0;
    if (m < M) {
        int hm = m / C;
        int kk = k - hm * Kph;
        if (kk >= 0 && kk < K) v = f2bf(W[(long long)kk * M + m]);
    }
    WT[i] = v;
}

__device__ __forceinline__ void prep1(const float* __restrict__ W, const float* __restrict__ a_src,
                                      const float* __restrict__ a_dst, unsigned short* __restrict__ WT,
                                      int K, int M, int C, int Kp, int H, int b, int lane) {
    int k = b % Kp;
    int th = b / Kp;
    int t = th / H;
    int h = th - t * H;
    size_t orow = (size_t)(M + t * H + h) * Kp;
    if (k >= K) {
        if (lane == 0) WT[orow + k] = 0;
        return;
    }
    const float* a = t ? a_dst : a_src;
    int hoff = h * C;
    const float* wrow = W + (size_t)k * M + hoff;
    float acc = 0.f;
    for (int c = lane; c < C; c += 64) acc += wrow[c] * a[hoff + c];
    for (int off = 32; off > 0; off >>= 1) acc += __shfl_down(acc, off);
    if (lane == 0) WT[orow + k] = f2bf(acc);
}

// fp32 variant: fout[th][Kp]
__device__ __forceinline__ void prep1f(const float* __restrict__ W, const float* __restrict__ a_src,
                                       const float* __restrict__ a_dst, float* __restrict__ fout,
                                       int K, int M, int C, int Kp, int H, int b, int lane) {
    int k = b % Kp;
    int th = b / Kp;
    int t = th / H;
    int h = th - t * H;
    if (k >= K) {
        if (lane == 0) fout[(size_t)th * Kp + k] = 0.f;
        return;
    }
    const float* a = t ? a_dst : a_src;
    int hoff = h * C;
    const float* wrow = W + (size_t)k * M + hoff;
    float acc = 0.f;
    for (int c = lane; c < C; c += 64) acc += wrow[c] * a[hoff + c];
    for (int off = 32; off > 0; off >>= 1) acc += __shfl_down(acc, off);
    if (lane == 0) fout[(size_t)th * Kp + k] = acc;
}

// ==================== kernel A: count ∪ cvt_w ∪ prep_va ∪ cvt_x ====================

__global__ __launch_bounds__(256) void k_A(
    const int* __restrict__ mol_dst, const int* __restrict__ pro_dst, int* __restrict__ cnt,
    int N_MOL, int E_MOL, int ET, int nb1,
    const float* __restrict__ W1, const float* __restrict__ W2, const float* __restrict__ W3,
    const float* __restrict__ Wp1, const float* __restrict__ Wp2, const float* __restrict__ Wp3,
    unsigned short* __restrict__ wt1, unsigned short* __restrict__ wt2bd, unsigned short* __restrict__ wt3,
    unsigned short* __restrict__ wtp1, unsigned short* __restrict__ wtp2bd, unsigned short* __restrict__ wtp3,
    const float* __restrict__ as1, const float* __restrict__ ad1,
    const float* __restrict__ as2, const float* __restrict__ ad2,
    const float* __restrict__ as3, const float* __restrict__ ad3,
    const float* __restrict__ aps2, const float* __restrict__ apd2,
    const float* __restrict__ aps3, const float* __restrict__ apd3,
    float* __restrict__ va2f, float* __restrict__ vap2f,
    const float* __restrict__ mol_x, unsigned short* __restrict__ xb,
    const float* __restrict__ pro_x, unsigned short* __restrict__ xpp,
    long long totM, long long totP) {
    const int nb2 = 957;   // cvt_w: 244872/256
    const int nb3 = 508;   // prep: 2032 units / 4 waves
    int b = blockIdx.x;
    int tid = threadIdx.x;
    if (b < nb1) {
        int i0 = b * 1024 + tid;
#pragma unroll
        for (int k = 0; k < 4; k++) {
            int e = i0 + k * 256;
            if (e < ET) {
                int d = (e < E_MOL) ? mol_dst[e] : (N_MOL + pro_dst[e - E_MOL]);
                atomicAdd(&cnt[d], 1);
            }
        }
    } else if (b < nb1 + nb2) {
        int idx = (b - nb1) * 256 + tid;
        if (idx < 12480)        cvtw1(W1, wt1, 78, 156, 80, idx);
        else if (idx < 114880)  cvtw_bd(W2, wt2bd, 156, 312, 156, 320, 160, idx - 12480);
        else if (idx < 214720)  cvtw1(W3, wt3, 312, 312, 320, idx - 114880);
        else if (idx < 216040)  cvtw1(Wp1, wtp1, 33, 33, 40, idx - 214720);
        else if (idx < 226920)  cvtw_bd(Wp2, wtp2bd, 33, 132, 66, 80, 40, idx - 216040);
        else if (idx < 244872)  cvtw1(Wp3, wtp3, 132, 132, 136, idx - 226920);
    } else if (b < nb1 + nb2 + nb3) {
        int unit = (b - nb1 - nb2) * 4 + (tid >> 6);
        int lane = tid & 63;
        if (unit < 320)        prep1(W1, as1, ad1, wt1, 78, 156, 78, 80, 2, unit, lane);
        else if (unit < 960)   prep1f(W2, as2, ad2, va2f, 156, 312, 156, 160, 2, unit - 320, lane);
        else if (unit < 1600)  prep1(W3, as3, ad3, wt3, 312, 312, 312, 320, 1, unit - 960, lane);
        else if (unit < 1760)  prep1f(Wp2, aps2, apd2, vap2f, 33, 132, 66, 40, 2, unit - 1600, lane);
        else if (unit < 2032)  prep1(Wp3, aps3, apd3, wtp3, 132, 132, 132, 136, 1, unit - 1760, lane);
    } else {
        long long i0 = (long long)(b - nb1 - nb2 - nb3) * 1024 + tid;
#pragma unroll
        for (int k = 0; k < 4; k++) {
            long long idx = i0 + k * 256;
            if (idx < totM) {
                int n = (int)(idx / 80);
                int kk = (int)(idx - (long long)n * 80);
                xb[idx] = (kk < 78) ? f2bf(mol_x[(long long)n * 78 + kk]) : (unsigned short)0;
            } else if (idx < totM + totP) {
                long long i2 = idx - totM;
                int n = (int)(i2 / 40);
                int kk = (int)(i2 - (long long)n * 40);
                xpp[i2] = (kk < 33) ? f2bf(pro_x[(long long)n * 33 + kk]) : (unsigned short)0;
            }
        }
    }
}

// ==================== scans ====================

__global__ __launch_bounds__(256) void k_scan1(const int* __restrict__ cnt, int* __restrict__ incl,
                                               int* __restrict__ bsums, int n) {
    __shared__ int sm[256];
    int i = blockIdx.x * 256 + threadIdx.x;
    int v = (i < n) ? cnt[i] : 0;
    sm[threadIdx.x] = v;
    __syncthreads();
    for (int off = 1; off < 256; off <<= 1) {
        int t = (threadIdx.x >= off) ? sm[threadIdx.x - off] : 0;
        __syncthreads();
        sm[threadIdx.x] += t;
        __syncthreads();
    }
    if (i < n) incl[i] = sm[threadIdx.x];
    if (threadIdx.x == 255) bsums[blockIdx.x] = sm[255];
}

__global__ __launch_bounds__(1024) void k_scan2(int* __restrict__ bsums, int nb) {
    __shared__ int sm[1024];
    int v = (threadIdx.x < nb) ? bsums[threadIdx.x] : 0;
    sm[threadIdx.x] = v;
    __syncthreads();
    for (int off = 1; off < 1024; off <<= 1) {
        int t = (threadIdx.x >= off) ? sm[threadIdx.x - off] : 0;
        __syncthreads();
        sm[threadIdx.x] += t;
        __syncthreads();
    }
    if (threadIdx.x < nb) bsums[threadIdx.x] = sm[threadIdx.x] - v;
}

__global__ __launch_bounds__(256) void k_scan3_all(const int* __restrict__ incl, const int* __restrict__ cnt,
                                                   const int* __restrict__ boff,
                                                   int* __restrict__ mol_rowp, int* __restrict__ pro_rowp,
                                                   int* __restrict__ cur,
                                                   int N_MOL, int N_PRO, int E_MOL, int E_PRO) {
    int i = blockIdx.x * 256 + threadIdx.x;
    int NT = N_MOL + N_PRO;
    if (i < NT) {
        int ex = incl[i] - cnt[i] + boff[blockIdx.x];
        cur[i] = ex;
        if (i < N_MOL) mol_rowp[i] = ex;
        else pro_rowp[i - N_MOL] = ex - E_MOL;
    }
    if (i == 0) {
        mol_rowp[N_MOL] = E_MOL;
        pro_rowp[N_PRO] = E_PRO;
    }
}

// ==================== kernel B: scatter ∪ GEMM ∪ GEMM ====================

__global__ __launch_bounds__(256) void k_B(
    const int* __restrict__ msrc, const int* __restrict__ mdst,
    const int* __restrict__ psrc, const int* __restrict__ pdst,
    const float* __restrict__ pw, int* __restrict__ cur, int2* __restrict__ cpack,
    int N_MOL, int E_MOL, int ET, int nbs,
    const unsigned short* __restrict__ A1, const unsigned short* __restrict__ B1,
    unsigned short* __restrict__ C1, float* __restrict__ as1o, float* __restrict__ ad1o,
    const float* __restrict__ bias1, int relu1, int zpad1,
    int N1, int Kp1, int M1, int Mext1, int Mp1, int H1, int g1x, int nb1,
    const unsigned short* __restrict__ A2, const unsigned short* __restrict__ B2,
    unsigned short* __restrict__ C2, float* __restrict__ as2o, float* __restrict__ ad2o,
    const float* __restrict__ bias2, int relu2, int zpad2,
    int N2, int Kp2, int M2, int Mext2, int Mp2, int H2, int g2x) {
    int b = blockIdx.x;
    if (b < nbs) {
        int e = b * 256 + threadIdx.x;
        if (e < ET) {
            int s, d;
            int wbits = 0;
            if (e >= E_MOL) {
                int ep = e - E_MOL;
                s = psrc[ep];
                d = N_MOL + pdst[ep];
                wbits = __float_as_int(pw[ep]);
            } else {
                s = msrc[e];
                d = mdst[e];
            }
            int pos = atomicAdd(&cur[d], 1);
            int2 pk;
            pk.x = s;
            pk.y = wbits;
            cpack[pos] = pk;
        }
    } else if (b < nbs + nb1) {
        int bb = b - nbs;
        gemm_body(A1, B1, C1, as1o, ad1o, bias1, relu1, zpad1, N1, Kp1, M1, Mext1, Mp1, H1, bb % g1x, bb / g1x);
    } else {
        int bb = b - nbs - nb1;
        gemm_body(A2, B2, C2, as2o, ad2o, bias2, relu2, zpad2, N2, Kp2, M2, Mext2, Mp2, H2, bb % g2x, bb / g2x);
    }
}

// ==================== deg/dinv ====================

__global__ __launch_bounds__(256) void k_deg(const int* __restrict__ rowp, const int2* __restrict__ cpack,
                                             float* __restrict__ dinv, int N) {
    int n = blockIdx.x * 256 + threadIdx.x;
    if (n < N) {
        int b = rowp[n], e = rowp[n + 1];
        float s = 0.f;
        for (int p = b; p < e; p++) s += __int_as_float(cpack[p].y);
        dinv[n] = rsqrtf(s + 1.0f);
    }
}

// ==================== fused dispatches ====================

// F1: mol conv1 agg (old, NEXTA->as2) ∪ pro gcn agg (old, NEXTA->asp2)
__global__ __launch_bounds__(NPB * 64) void k_fuse1(
    const unsigned short* __restrict__ hb, const float* __restrict__ asm_, const float* __restrict__ adm_,
    const int* __restrict__ mrowp, const int2* __restrict__ mcp, const float* __restrict__ b1,
    unsigned short* __restrict__ x2m, const float* __restrict__ va2f,
    float* __restrict__ asm2, float* __restrict__ adm2, int Nm,
    const unsigned short* __restrict__ hbp, const float* __restrict__ dinv,
    const int* __restrict__ prowp, const int2* __restrict__ pcp, const float* __restrict__ bp1,
    unsigned short* __restrict__ x2p, const float* __restrict__ vap2f,
    float* __restrict__ asp2, float* __restrict__ adp2, int Np, int nb1) {
    int wave = threadIdx.x >> 6, lane = threadIdx.x & 63;
    int b = blockIdx.x;
    if (b < nb1) {
        int n = b * NPB + wave;
        if (n < Nm)
            agg_body<20, 3, 2, true, 1, false, true>(hb, asm_, adm_, nullptr, mrowp, mcp, b1,
                                                     nullptr, x2m, va2f, 160, asm2, adm2,
                                                     156, 160, 1, n, lane);
    } else {
        int n = (b - nb1) * NPB + wave;
        if (n < Np)
            agg_body<5, 8, 1, false, 1, true, true>(hbp, nullptr, nullptr, dinv, prowp, pcp, bp1,
                                                    nullptr, x2p, vap2f, 40, asp2, adp2,
                                                    33, 40, 1, n, lane);
    }
}

// F2: mol conv2 input-space agg ∪ pro conv2 input-space agg
__global__ __launch_bounds__(NPB * 64) void k_fuseN(
    const unsigned short* __restrict__ x2m, const float* __restrict__ asm2, const float* __restrict__ adm2,
    const int* __restrict__ mrowp, const int2* __restrict__ mcp, unsigned short* __restrict__ xa2m, int Nm,
    const unsigned short* __restrict__ x2p, const float* __restrict__ asp2, const float* __restrict__ adp2,
    const int* __restrict__ prowp, const int2* __restrict__ pcp, unsigned short* __restrict__ xa2p, int Np,
    int nb1) {
    int wave = threadIdx.x >> 6, lane = threadIdx.x & 63;
    int b = blockIdx.x;
    if (b < nb1) {
        int n = b * NPB + wave;
        if (n < Nm) aggN_body<20, 3>(x2m, asm2, adm2, mrowp, mcp, xa2m, n, lane);
    } else {
        int n = (b - nb1) * NPB + wave;
        if (n < Np) aggN_body<5, 8>(x2p, asp2, adp2, prowp, pcp, xa2p, n, lane);
    }
}

// F5: mol conv3 agg (fp32 out, no relu) ∪ pro conv3 agg (fp32 out, relu)
__global__ __launch_bounds__(NPB * 64) void k_fuse5(
    const unsigned short* __restrict__ hb, const float* __restrict__ asm_, const float* __restrict__ adm_,
    const int* __restrict__ mrowp, const int2* __restrict__ mcp, const float* __restrict__ b3,
    float* __restrict__ out_mol, int Nm,
    const unsigned short* __restrict__ hbp, const float* __restrict__ asp_, const float* __restrict__ adp_,
    const int* __restrict__ prowp, const int2* __restrict__ pcp, const float* __restrict__ bp3,
    float* __restrict__ out_pro, int Np, int nb1) {
    int wave = threadIdx.x >> 6, lane = threadIdx.x & 63;
    int b = blockIdx.x;
    if (b < nb1) {
        int n = b * NPB + wave;
        if (n < Nm)
            agg_body<20, 3, 1, true, 2, false, false>(hb, asm_, adm_, nullptr, mrowp, mcp, b3,
                                                      out_mol, nullptr, nullptr, 0, nullptr, nullptr,
                                                      312, 320, 0, n, lane);
    } else {
        int n = (b - nb1) * NPB + wave;
        if (n < Np)
            agg_body<17, 3, 1, true, 1, false, false>(hbp, asp_, adp_, nullptr, prowp, pcp, bp3,
                                                      out_pro, nullptr, nullptr, 0, nullptr, nullptr,
                                                      132, 136, 1, n, lane);
    }
}

// ==================== launch ====================

extern "C" void kernel_launch(void* const* d_in, const int* in_sizes, int n_in,
                              void* d_out, int out_size, void* d_ws, size_t ws_size,
                              hipStream_t stream) {
    const int N_MOL = in_sizes[0] / 78;
    const int E_MOL = in_sizes[1] / 2;
    const int N_PRO = in_sizes[2] / 33;
    const int E_PRO = in_sizes[3] / 2;
    const int NT = N_MOL + N_PRO;
    const int ET = E_MOL + E_PRO;

    const float* mol_x = (const float*)d_in[0];
    const int* mol_ei = (const int*)d_in[1];
    const float* pro_x = (const float*)d_in[2];
    const int* pro_ei = (const int*)d_in[3];
    const float* pro_ew = (const float*)d_in[4];
    const float *W1 = (const float*)d_in[5], *as1 = (const float*)d_in[6], *ad1 = (const float*)d_in[7],
                *b1 = (const float*)d_in[8];
    const float *W2 = (const float*)d_in[9], *as2 = (const float*)d_in[10], *ad2 = (const float*)d_in[11],
                *b2 = (const float*)d_in[12];
    const float *W3 = (const float*)d_in[13], *as3 = (const float*)d_in[14], *ad3 = (const float*)d_in[15],
                *b3 = (const float*)d_in[16];
    const float *Wp1 = (const float*)d_in[17], *bp1 = (const float*)d_in[18];
    const float *Wp2 = (const float*)d_in[19], *aps2 = (const float*)d_in[20], *apd2 = (const float*)d_in[21],
                *bp2 = (const float*)d_in[22];
    const float *Wp3 = (const float*)d_in[23], *aps3 = (const float*)d_in[24], *apd3 = (const float*)d_in[25],
                *bp3 = (const float*)d_in[26];

    float* out_mol = (float*)d_out;
    float* out_pro = (float*)d_out + (size_t)N_MOL * 312;

    // ---------- d_out as scratch for buffers dead before F5 ----------
    // out_size = (N_MOL*312 + N_PRO*132)*4 = 115.2 MB; scratch uses first ~91.2 MB.
    // xa2m [F2->F3], xa2p [F2->F3], xb0/xp0 [A->B1], xpp [F3->F4]; F5 rewrites all of d_out.
    char* ob = (char*)d_out;
    size_t o_xa2m = 0;
    size_t o_xa2p = o_xa2m + (size_t)N_MOL * 320 * 2;                 // 32.0 MB
    size_t o_xb0  = o_xa2p + (size_t)N_PRO * 80 * 2;                  // 48.0 MB
    size_t o_xp0  = o_xb0 + (size_t)N_MOL * 80 * 2;                   // 56.0 MB
    size_t o_xpp  = o_xp0 + (size_t)N_PRO * 40 * 2;                   // 64.0 MB (+27.2 = 91.2 <= 115.2)
    unsigned short* xa2m = (unsigned short*)(ob + o_xa2m);
    unsigned short* xa2p = (unsigned short*)(ob + o_xa2p);
    unsigned short* xb0  = (unsigned short*)(ob + o_xb0);
    unsigned short* xp0  = (unsigned short*)(ob + o_xp0);
    unsigned short* xpp  = (unsigned short*)(ob + o_xpp);

    // ---------- workspace (~107 MB; round-5's proven-good footprint was 131 MB) ----------
    char* p = (char*)d_ws;
    auto alloc = [&](size_t bytes) -> void* {
        void* r = (void*)p;
        p += (bytes + 255) & ~(size_t)255;
        return r;
    };
    int* cnt_all  = (int*)alloc((size_t)NT * 4);
    int* incl     = (int*)alloc((size_t)NT * 4);
    int* cur_all  = (int*)alloc((size_t)NT * 4);
    int* bsums    = (int*)alloc(1024 * 4);
    int* mol_rowp = (int*)alloc((size_t)(N_MOL + 1) * 4);
    int* pro_rowp = (int*)alloc((size_t)(N_PRO + 1) * 4);
    int2* cpack   = (int2*)alloc((size_t)ET * 8);
    float* dinv   = (float*)alloc((size_t)N_PRO * 4);
    float* asb_m  = (float*)alloc((size_t)N_MOL * 2 * 4);  // layer1 / layer3 alpha (mol)
    float* adb_m  = (float*)alloc((size_t)N_MOL * 2 * 4);
    float* asb_m2 = (float*)alloc((size_t)N_MOL * 2 * 4);  // layer2 alpha (mol)
    float* adb_m2 = (float*)alloc((size_t)N_MOL * 2 * 4);
    float* asb_p  = (float*)alloc((size_t)N_PRO * 2 * 4);  // layer p3 alpha
    float* adb_p  = (float*)alloc((size_t)N_PRO * 2 * 4);
    float* asb_p2 = (float*)alloc((size_t)N_PRO * 2 * 4);  // layer p2 alpha
    float* adb_p2 = (float*)alloc((size_t)N_PRO * 2 * 4);
    float* va2f   = (float*)alloc((size_t)4 * 160 * 4);
    float* vap2f  = (float*)alloc((size_t)4 * 40 * 4);
    // bufA: {mol h1 [B1->F1, ld160]} then {x3m [F3->F4, ld320]}
    unsigned short* bufA = (unsigned short*)alloc((size_t)N_MOL * 320 * 2);
    // bufB: {x2m [F1->F2, ld160] + x2p [F1->F2, ld40]} then {mol h3 [F4->F5, ld320]}
    unsigned short* bufB = (unsigned short*)alloc((size_t)N_MOL * 320 * 2);
    // bufC: {pro h1 [B1->F1, ld40]} then {pro h3 [F4->F5, ld136]}
    unsigned short* bufC = (unsigned short*)alloc((size_t)N_PRO * 136 * 2);
    unsigned short* wt1    = (unsigned short*)alloc((size_t)160 * 80 * 2);
    unsigned short* wt2bd  = (unsigned short*)alloc((size_t)320 * 320 * 2);
    unsigned short* wt3    = (unsigned short*)alloc((size_t)320 * 320 * 2);
    unsigned short* wtp1   = (unsigned short*)alloc((size_t)40 * 40 * 2);
    unsigned short* wtp2bd = (unsigned short*)alloc((size_t)136 * 80 * 2);
    unsigned short* wtp3   = (unsigned short*)alloc((size_t)136 * 136 * 2);
    (void)ws_size;

    unsigned short* hb1  = bufA;                       // mol GEMM1 out, ld160
    unsigned short* x3m  = bufA;                       // F3 mol out, ld320
    unsigned short* x2m  = bufB;                       // F1 mol out, ld160
    unsigned short* x2p  = bufB + (size_t)N_MOL * 160; // F1 pro out, ld40
    unsigned short* hb3  = bufB;                       // F4 mol out, ld320
    unsigned short* hbp1 = bufC;                       // pro GEMM1 out, ld40
    unsigned short* hbp3 = bufC;                       // F4 pro out, ld136

    int2* mol_cp = cpack;
    int2* pro_cp = cpack + E_MOL;

    const int* mol_src = mol_ei;
    const int* mol_dst = mol_ei + E_MOL;
    const int* pro_src = pro_ei;
    const int* pro_dst = pro_ei + E_PRO;

    const long long totM = (long long)N_MOL * 80;
    const long long totP = (long long)N_PRO * 40;

    // ---- A: count ∪ cvt_w ∪ prep_va ∪ cvt_x ----
    hipMemsetAsync(cnt_all, 0, (size_t)NT * 4, stream);
    int nbCnt = (ET + 1023) / 1024;
    int nbCvx = (int)((totM + totP + 1023) / 1024);
    int gridA = nbCnt + 957 + 508 + nbCvx;
    k_A<<<gridA, 256, 0, stream>>>(mol_dst, pro_dst, cnt_all, N_MOL, E_MOL, ET, nbCnt,
                                   W1, W2, W3, Wp1, Wp2, Wp3, wt1, wt2bd, wt3, wtp1, wtp2bd, wtp3,
                                   as1, ad1, as2, ad2, as3, ad3, aps2, apd2, aps3, apd3,
                                   va2f, vap2f, mol_x, xb0, pro_x, xp0, totM, totP);

    // ---- scans ----
    int nbT = (NT + 255) / 256;
    k_scan1<<<nbT, 256, 0, stream>>>(cnt_all, incl, bsums, NT);
    k_scan2<<<1, 1024, 0, stream>>>(bsums, nbT);
    k_scan3_all<<<nbT, 256, 0, stream>>>(incl, cnt_all, bsums, mol_rowp, pro_rowp, cur_all,
                                         N_MOL, N_PRO, E_MOL, E_PRO);

    int gyM = (N_MOL + TBM - 1) / TBM;
    int gyP = (N_PRO + TBM - 1) / TBM;

    // ---- B1: scatter ∪ GEMM1m (old, alpha rows) ∪ GEMMp1 (plain) ----
    {
        int nbs = (ET + 255) / 256;
        int g1x = 2;                       // Mext=160
        int nb1 = g1x * gyM;
        int g2x = 1;                       // Mext=33
        k_B<<<nbs + nb1 + g2x * gyP, 256, 0, stream>>>(
            mol_src, mol_dst, pro_src, pro_dst, pro_ew, cur_all, cpack, N_MOL, E_MOL, ET, nbs,
            xb0, wt1, hb1, asb_m, adb_m, nullptr, 0, 0, N_MOL, 80, 156, 160, 160, 2, g1x, nb1,
            xp0, wtp1, hbp1, nullptr, nullptr, nullptr, 0, 0, N_PRO, 40, 33, 33, 40, 0, g2x);
    }

    k_deg<<<(N_PRO + 255) / 256, 256, 0, stream>>>(pro_rowp, pro_cp, dinv, N_PRO);

    // ---- F1: agg1m (->x2m, as2) ∪ gcn agg (->x2p, asp2) ----
    {
        int nb1 = (N_MOL + NPB - 1) / NPB;
        int nb2 = (N_PRO + NPB - 1) / NPB;
        k_fuse1<<<nb1 + nb2, NPB * 64, 0, stream>>>(hb1, asb_m, adb_m, mol_rowp, mol_cp, b1,
                                                    x2m, va2f, asb_m2, adb_m2, N_MOL,
                                                    hbp1, dinv, pro_rowp, pro_cp, bp1,
                                                    x2p, vap2f, asb_p2, adb_p2, N_PRO, nb1);
    }

    // ---- F2: input-space aggs (x2m -> xa2m) ∪ (x2p -> xa2p) ----
    {
        int nb1 = (N_MOL + NPB - 1) / NPB;
        int nb2 = (N_PRO + NPB - 1) / NPB;
        k_fuseN<<<nb1 + nb2, NPB * 64, 0, stream>>>(x2m, asb_m2, adb_m2, mol_rowp, mol_cp, xa2m, N_MOL,
                                                    x2p, asb_p2, adb_p2, pro_rowp, pro_cp, xa2p, N_PRO, nb1);
    }

    // ---- F3: block-diag GEMMs: xa2m@wt2bd -> x3m (+b2,relu) ∪ xa2p@wtp2bd -> xpp (+bp2,relu) ----
    {
        int g1x = 3;                       // Mext=320
        int nb1 = g1x * gyM;
        int g2x = 2;                       // Mext=136
        k_B<<<nb1 + g2x * gyP, 256, 0, stream>>>(
            nullptr, nullptr, nullptr, nullptr, nullptr, nullptr, nullptr, N_MOL, E_MOL, ET, 0,
            xa2m, wt2bd, x3m, nullptr, nullptr, b2, 1, 320, N_MOL, 320, 312, 320, 320, 0, g1x, nb1,
            xa2p, wtp2bd, xpp, nullptr, nullptr, bp2, 1, 136, N_PRO, 80, 132, 136, 136, 0, g2x);
    }

    // ---- F4: GEMM3m (old, alpha) ∪ GEMMp3 (old, alpha) ----
    {
        int g1x = 3;                       // Mext=314
        int nb1 = g1x * gyM;
        int g2x = 2;                       // Mext=134
        k_B<<<nb1 + g2x * gyP, 256, 0, stream>>>(
            nullptr, nullptr, nullptr, nullptr, nullptr, nullptr, nullptr, N_MOL, E_MOL, ET, 0,
            x3m, wt3, hb3, asb_m, adb_m, nullptr, 0, 0, N_MOL, 320, 312, 314, 320, 1, g1x, nb1,
            xpp, wtp3, hbp3, asb_p, adb_p, nullptr, 0, 0, N_PRO, 136, 132, 134, 136, 1, g2x);
    }

    // ---- F5: final aggs -> outputs ----
    {
        int nb1 = (N_MOL + NPB - 1) / NPB;
        int nb2 = (N_PRO + NPB - 1) / NPB;
        k_fuse5<<<nb1 + nb2, NPB * 64, 0, stream>>>(hb3, asb_m, adb_m, mol_rowp, mol_cp, b3, out_mol, N_MOL,
                                                    hbp3, asb_p, adb_p, pro_rowp, pro_cp, bp3, out_pro, N_PRO, nb1);
    }
}

// Round 8
// 707.117 us; speedup vs baseline: 1.1917x; 1.1917x over previous
//
#include <hip/hip_runtime.h>
#include <cstdint>
#include <cstddef>

#define WAVE 64
#define NPB 4   // waves per aggregation block

#define TBM 128
#define TBN 128
#define TBK 32
#define LDK 40

typedef short s16x8 __attribute__((ext_vector_type(8)));
typedef float f32x4 __attribute__((ext_vector_type(4)));

__device__ __forceinline__ unsigned short f2bf(float f) {
    unsigned int u = __float_as_uint(f);
    unsigned int r = (u + 0x7fffu + ((u >> 16) & 1u)) >> 16;
    return (unsigned short)r;
}
__device__ __forceinline__ float bf2f_lo(unsigned int v) { return __uint_as_float(v << 16); }
__device__ __forceinline__ float bf2f_hi(unsigned int v) { return __uint_as_float(v & 0xffff0000u); }
__device__ __forceinline__ float lrelu02(float e) { return (e > 0.f) ? e : 0.2f * e; }

// ==================== GEMM body ====================

__device__ __forceinline__ void gemm_body(const unsigned short* __restrict__ A,
                                          const unsigned short* __restrict__ BT,
                                          unsigned short* __restrict__ Cbf,
                                          float* __restrict__ asb, float* __restrict__ adb,
                                          const float* __restrict__ bias, int relu, int zpadTo,
                                          int N, int Kp, int M, int Mext, int Mp, int H,
                                          int bx, int by) {
    __shared__ __align__(16) unsigned short As[TBM * LDK];
    __shared__ __align__(16) unsigned short Bs[TBN * LDK];
    int tid = threadIdx.x;
    int wave = tid >> 6;
    int lane = tid & 63;
    int rowBase = by * TBM;
    int colBase = bx * TBN;
    int wm = (wave & 1) * 64;
    int wn = (wave >> 1) * 64;
    int l15 = lane & 15;
    int quad = lane >> 4;

    f32x4 acc[4][4];
    f32x4 z4 = {0.f, 0.f, 0.f, 0.f};
#pragma unroll
    for (int i = 0; i < 4; i++)
#pragma unroll
        for (int j = 0; j < 4; j++) acc[i][j] = z4;

    int srow = tid >> 2;
    int skg = tid & 3;
    const uint4 zero16 = {0u, 0u, 0u, 0u};

    for (int k0 = 0; k0 < Kp; k0 += TBK) {
#pragma unroll
        for (int half = 0; half < 2; half++) {
            int row = srow + half * 64;
            int gk = k0 + skg * 8;
            bool kok = (gk < Kp);
            {
                int gr = rowBase + row;
                uint4 v = zero16;
                if (kok && gr < N) v = *(const uint4*)(A + (size_t)gr * Kp + gk);
                *(uint4*)(As + row * LDK + skg * 8) = v;
            }
            {
                int gc = colBase + row;
                uint4 v = zero16;
                if (kok && gc < Mext) v = *(const uint4*)(BT + (size_t)gc * Kp + gk);
                *(uint4*)(Bs + row * LDK + skg * 8) = v;
            }
        }
        __syncthreads();

        s16x8 af[4], bfr[4];
#pragma unroll
        for (int mt = 0; mt < 4; mt++)
            af[mt] = *(const s16x8*)(As + (wm + mt * 16 + l15) * LDK + quad * 8);
#pragma unroll
        for (int nt = 0; nt < 4; nt++)
            bfr[nt] = *(const s16x8*)(Bs + (wn + nt * 16 + l15) * LDK + quad * 8);
#pragma unroll
        for (int mt = 0; mt < 4; mt++)
#pragma unroll
            for (int nt = 0; nt < 4; nt++)
                acc[mt][nt] = __builtin_amdgcn_mfma_f32_16x16x32_bf16(af[mt], bfr[nt], acc[mt][nt], 0, 0, 0);
        __syncthreads();
    }

#pragma unroll
    for (int mt = 0; mt < 4; mt++) {
#pragma unroll
        for (int r = 0; r < 4; r++) {
            int row = rowBase + wm + mt * 16 + quad * 4 + r;
            if (row < N) {
#pragma unroll
                for (int nt = 0; nt < 4; nt++) {
                    int col = colBase + wn + nt * 16 + l15;
                    float v = acc[mt][nt][r];
                    if (col < M) {
                        float v2 = v;
                        if (bias != nullptr) {
                            v2 += bias[col];
                            if (relu) v2 = fmaxf(v2, 0.f);
                        }
                        Cbf[(size_t)row * Mp + col] = f2bf(v2);
                    } else if (col < zpadTo) {
                        Cbf[(size_t)row * Mp + col] = 0;
                    } else if (asb != nullptr && col < M + 2 * H) {
                        int t = col - M;
                        if (t < H) asb[(size_t)row * H + t] = v;
                        else adb[(size_t)row * H + (t - H)] = v;
                    }
                }
            }
        }
    }
}

// ==================== group-per-node aggregation (h-space) ====================
// Wave = NG groups of SLOTS lanes; each group owns ONE node entirely.
// Per edge: whole group loads the same cpack/as (HW broadcast), computes the weight
// redundantly in-lane, gathers its own 16B slot, FMAs. No bpermute, no cross-group
// reduce, no softmax shuffle (wsum replicated in-lane). Edge loop unrolled x2.
// NEXTA: next layer's alpha logits via guarded shfl_down tree over the group.

template <int SLOTS, int NG, int H, bool SM, int SWEEPS, bool GCN, bool NEXTA>
__device__ __forceinline__ void agg_gp(const unsigned short* __restrict__ hfeat,
                                       const float* __restrict__ as_, const float* __restrict__ ad_,
                                       const float* __restrict__ dinv,
                                       const int* __restrict__ rowp, const int2* __restrict__ cpack,
                                       const float* __restrict__ bias,
                                       float* __restrict__ out_f, unsigned short* __restrict__ out_bf,
                                       const float* __restrict__ vanf, int vald,
                                       float* __restrict__ asn, float* __restrict__ adn_o,
                                       int HC, int ldo, int relu, int nbase, int lane, int N) {
    constexpr int ROWB = SWEEPS * SLOTS * 16;
    int g = lane / SLOTS;
    int slot = lane - g * SLOTS;
    int n = nbase + g;
    if (g >= NG || n >= N) return;
    int C = HC / H;
    int beg = rowp[n], end = rowp[n + 1];

    float adn[H], msub[H];
    float di = 0.f, sfw;
    if (GCN) {
        di = dinv[n];
        sfw = di * di;
    } else {
#pragma unroll
        for (int h = 0; h < H; h++) {
            adn[h] = ad_[(size_t)n * H + h];
            msub[h] = lrelu02(as_[(size_t)n * H + h] + adn[h]);
        }
        sfw = 1.f;
    }

    int ch0[SWEEPS];
    bool h1q[SWEEPS][4];
#pragma unroll
    for (int sw = 0; sw < SWEEPS; sw++) {
        ch0[sw] = (sw * SLOTS + slot) * 8;
#pragma unroll
        for (int q = 0; q < 4; q++) h1q[sw][q] = (H == 2) && ((ch0[sw] + 2 * q) >= C);
    }

    float accx[SWEEPS][4], accy[SWEEPS][4];
#pragma unroll
    for (int sw = 0; sw < SWEEPS; sw++) {
        uint4 v = *(const uint4*)((const char*)hfeat + (size_t)n * ROWB + (sw * SLOTS + slot) * 16);
        unsigned int vv[4] = {v.x, v.y, v.z, v.w};
#pragma unroll
        for (int q = 0; q < 4; q++) { accx[sw][q] = sfw * bf2f_lo(vv[q]); accy[sw][q] = sfw * bf2f_hi(vv[q]); }
    }

    float wsum[H];
#pragma unroll
    for (int h = 0; h < H; h++) wsum[h] = 0.f;

    int p = beg;
    for (; p + 1 < end; p += 2) {
        int2 pk0 = cpack[p];
        int2 pk1 = cpack[p + 1];
        int s0 = pk0.x, s1 = pk1.x;
        float w0[H], w1[H];
        if (GCN) {
            w0[0] = dinv[s0] * __int_as_float(pk0.y) * di;
            w1[0] = dinv[s1] * __int_as_float(pk1.y) * di;
        } else {
#pragma unroll
            for (int h = 0; h < H; h++) {
                w0[h] = __expf(lrelu02(as_[(size_t)s0 * H + h] + adn[h]) - msub[h]);
                w1[h] = __expf(lrelu02(as_[(size_t)s1 * H + h] + adn[h]) - msub[h]);
            }
        }
        if (SM) {
#pragma unroll
            for (int h = 0; h < H; h++) wsum[h] += w0[h] + w1[h];
        }
        uint4 v0[SWEEPS], v1[SWEEPS];
#pragma unroll
        for (int sw = 0; sw < SWEEPS; sw++)
            v0[sw] = *(const uint4*)((const char*)hfeat + (size_t)s0 * ROWB + (sw * SLOTS + slot) * 16);
#pragma unroll
        for (int sw = 0; sw < SWEEPS; sw++)
            v1[sw] = *(const uint4*)((const char*)hfeat + (size_t)s1 * ROWB + (sw * SLOTS + slot) * 16);
#pragma unroll
        for (int sw = 0; sw < SWEEPS; sw++) {
            unsigned int a0[4] = {v0[sw].x, v0[sw].y, v0[sw].z, v0[sw].w};
            unsigned int a1[4] = {v1[sw].x, v1[sw].y, v1[sw].z, v1[sw].w};
#pragma unroll
            for (int q = 0; q < 4; q++) {
                float wq0 = (H == 2) ? (h1q[sw][q] ? w0[1] : w0[0]) : w0[0];
                float wq1 = (H == 2) ? (h1q[sw][q] ? w1[1] : w1[0]) : w1[0];
                accx[sw][q] += wq0 * bf2f_lo(a0[q]) + wq1 * bf2f_lo(a1[q]);
                accy[sw][q] += wq0 * bf2f_hi(a0[q]) + wq1 * bf2f_hi(a1[q]);
            }
        }
    }
    if (p < end) {
        int2 pk0 = cpack[p];
        int s0 = pk0.x;
        float w0[H];
        if (GCN) {
            w0[0] = dinv[s0] * __int_as_float(pk0.y) * di;
        } else {
#pragma unroll
            for (int h = 0; h < H; h++)
                w0[h] = __expf(lrelu02(as_[(size_t)s0 * H + h] + adn[h]) - msub[h]);
        }
        if (SM) {
#pragma unroll
            for (int h = 0; h < H; h++) wsum[h] += w0[h];
        }
        uint4 v0[SWEEPS];
#pragma unroll
        for (int sw = 0; sw < SWEEPS; sw++)
            v0[sw] = *(const uint4*)((const char*)hfeat + (size_t)s0 * ROWB + (sw * SLOTS + slot) * 16);
#pragma unroll
        for (int sw = 0; sw < SWEEPS; sw++) {
            unsigned int a0[4] = {v0[sw].x, v0[sw].y, v0[sw].z, v0[sw].w};
#pragma unroll
            for (int q = 0; q < 4; q++) {
                float wq0 = (H == 2) ? (h1q[sw][q] ? w0[1] : w0[0]) : w0[0];
                accx[sw][q] += wq0 * bf2f_lo(a0[q]);
                accy[sw][q] += wq0 * bf2f_hi(a0[q]);
            }
        }
    }

    float rs[H];
    if (SM) {
#pragma unroll
        for (int h = 0; h < H; h++) rs[h] = 1.f / (1.f + wsum[h] + 1e-16f);  // +1 = self term
    } else {
#pragma unroll
        for (int h = 0; h < H; h++) rs[h] = 1.f;
    }

    float ps[4] = {0.f, 0.f, 0.f, 0.f};
#pragma unroll
    for (int sw = 0; sw < SWEEPS; sw++) {
        float o[8];
#pragma unroll
        for (int q = 0; q < 4; q++) {
            float r = (H == 2) ? (h1q[sw][q] ? rs[1] : rs[0]) : rs[0];
            int c0 = ch0[sw] + 2 * q;
            float b0 = (c0 < HC) ? bias[c0] : 0.f;
            float b1v = (c0 + 1 < HC) ? bias[c0 + 1] : 0.f;
            float o0 = accx[sw][q] * r + b0;
            float o1 = accy[sw][q] * r + b1v;
            if (relu) { o0 = fmaxf(o0, 0.f); o1 = fmaxf(o1, 0.f); }
            if (c0 >= HC) o0 = 0.f;
            if (c0 + 1 >= HC) o1 = 0.f;
            o[2 * q] = o0;
            o[2 * q + 1] = o1;
        }
        if (NEXTA) {
#pragma unroll
            for (int j = 0; j < 8; j++) {
                int c = ch0[sw] + j;
#pragma unroll
                for (int th = 0; th < 4; th++) ps[th] += o[j] * vanf[th * vald + c];
            }
        }
        if (out_bf) {
            uint4 pk;
            unsigned* pp = (unsigned*)&pk;
#pragma unroll
            for (int q = 0; q < 4; q++)
                pp[q] = (unsigned)f2bf(o[2 * q]) | ((unsigned)f2bf(o[2 * q + 1]) << 16);
            *(uint4*)((char*)out_bf + (size_t)n * ((size_t)ldo * 2) + (sw * SLOTS + slot) * 16) = pk;
        } else {
#pragma unroll
            for (int half = 0; half < 2; half++) {
                int c0 = ch0[sw] + half * 4;
                if (c0 < HC) {
                    float4 f4 = make_float4(o[half * 4], o[half * 4 + 1], o[half * 4 + 2], o[half * 4 + 3]);
                    *(float4*)(out_f + (size_t)n * HC + c0) = f4;
                }
            }
        }
    }
    if (NEXTA) {
        // guarded shfl_down tree over the group's SLOTS lanes (valid at slot 0)
        constexpr int P = SLOTS >= 32 ? 32 : SLOTS >= 16 ? 16 : SLOTS >= 8 ? 8 : SLOTS >= 4 ? 4 : SLOTS >= 2 ? 2 : 1;
        if (P < SLOTS) {
#pragma unroll
            for (int th = 0; th < 4; th++) {
                float t = __shfl_down(ps[th], P);
                if (slot + P < SLOTS) ps[th] += t;
            }
        }
#pragma unroll
        for (int off = P >> 1; off > 0; off >>= 1) {
#pragma unroll
            for (int th = 0; th < 4; th++) {
                float t = __shfl_down(ps[th], off);
                if (slot + off < P) ps[th] += t;
            }
        }
        if (slot == 0) {
            asn[(size_t)n * 2 + 0] = ps[0];
            asn[(size_t)n * 2 + 1] = ps[1];
            adn_o[(size_t)n * 2 + 0] = ps[2];
            adn_o[(size_t)n * 2 + 1] = ps[3];
        }
    }
}

// ==================== group-per-node input-space aggregation (H=2) ====================
// Gathers INPUT rows, per-head weighted sums, writes block-diag A2 [n][2][SLOTS*8] bf16.

template <int SLOTS, int NG>
__device__ __forceinline__ void aggN_gp(const unsigned short* __restrict__ x,
                                        const float* __restrict__ as_, const float* __restrict__ ad_,
                                        const int* __restrict__ rowp, const int2* __restrict__ cpack,
                                        unsigned short* __restrict__ A2, int nbase, int lane, int N) {
    constexpr int ROWB = SLOTS * 16;
    int g = lane / SLOTS;
    int slot = lane - g * SLOTS;
    int n = nbase + g;
    if (g >= NG || n >= N) return;
    int beg = rowp[n], end = rowp[n + 1];

    float adn[2], msub[2];
#pragma unroll
    for (int h = 0; h < 2; h++) {
        adn[h] = ad_[(size_t)n * 2 + h];
        msub[h] = lrelu02(as_[(size_t)n * 2 + h] + adn[h]);
    }

    float ax[2][4], ay[2][4];
    {
        uint4 v = *(const uint4*)((const char*)x + (size_t)n * ROWB + slot * 16);
        unsigned int vv[4] = {v.x, v.y, v.z, v.w};
#pragma unroll
        for (int q = 0; q < 4; q++) {
            float lo = bf2f_lo(vv[q]), hi = bf2f_hi(vv[q]);
            ax[0][q] = lo; ax[1][q] = lo;
            ay[0][q] = hi; ay[1][q] = hi;
        }
    }
    float wsum[2] = {0.f, 0.f};

    int p = beg;
    for (; p + 1 < end; p += 2) {
        int s0 = cpack[p].x;
        int s1 = cpack[p + 1].x;
        float w0[2], w1[2];
#pragma unroll
        for (int h = 0; h < 2; h++) {
            w0[h] = __expf(lrelu02(as_[(size_t)s0 * 2 + h] + adn[h]) - msub[h]);
            w1[h] = __expf(lrelu02(as_[(size_t)s1 * 2 + h] + adn[h]) - msub[h]);
        }
        wsum[0] += w0[0] + w1[0];
        wsum[1] += w0[1] + w1[1];
        uint4 v0 = *(const uint4*)((const char*)x + (size_t)s0 * ROWB + slot * 16);
        uint4 v1 = *(const uint4*)((const char*)x + (size_t)s1 * ROWB + slot * 16);
        unsigned int a0[4] = {v0.x, v0.y, v0.z, v0.w};
        unsigned int a1[4] = {v1.x, v1.y, v1.z, v1.w};
#pragma unroll
        for (int q = 0; q < 4; q++) {
            float lo0 = bf2f_lo(a0[q]), hi0 = bf2f_hi(a0[q]);
            float lo1 = bf2f_lo(a1[q]), hi1 = bf2f_hi(a1[q]);
            ax[0][q] += w0[0] * lo0 + w1[0] * lo1;
            ax[1][q] += w0[1] * lo0 + w1[1] * lo1;
            ay[0][q] += w0[0] * hi0 + w1[0] * hi1;
            ay[1][q] += w0[1] * hi0 + w1[1] * hi1;
        }
    }
    if (p < end) {
        int s0 = cpack[p].x;
        float w0[2];
#pragma unroll
        for (int h = 0; h < 2; h++)
            w0[h] = __expf(lrelu02(as_[(size_t)s0 * 2 + h] + adn[h]) - msub[h]);
        wsum[0] += w0[0];
        wsum[1] += w0[1];
        uint4 v0 = *(const uint4*)((const char*)x + (size_t)s0 * ROWB + slot * 16);
        unsigned int a0[4] = {v0.x, v0.y, v0.z, v0.w};
#pragma unroll
        for (int q = 0; q < 4; q++) {
            float lo0 = bf2f_lo(a0[q]), hi0 = bf2f_hi(a0[q]);
            ax[0][q] += w0[0] * lo0;
            ax[1][q] += w0[1] * lo0;
            ay[0][q] += w0[0] * hi0;
            ay[1][q] += w0[1] * hi0;
        }
    }

    float rs[2];
#pragma unroll
    for (int h = 0; h < 2; h++) rs[h] = 1.f / (1.f + wsum[h] + 1e-16f);

#pragma unroll
    for (int h = 0; h < 2; h++) {
        uint4 pk;
        unsigned* pp = (unsigned*)&pk;
#pragma unroll
        for (int q = 0; q < 4; q++) {
            float o0 = ax[h][q] * rs[h];
            float o1 = ay[h][q] * rs[h];
            pp[q] = (unsigned)f2bf(o0) | ((unsigned)f2bf(o1) << 16);
        }
        *(uint4*)((char*)A2 + (size_t)n * (2 * ROWB) + h * ROWB + slot * 16) = pk;
    }
}

// ==================== helpers for kernel A ====================

__device__ __forceinline__ void cvtw1(const float* __restrict__ W, unsigned short* __restrict__ WT,
                                      int K, int M, int Kp, int i) {
    int m = i / Kp;
    int k = i - m * Kp;
    WT[i] = (k < K) ? f2bf(W[(long long)k * M + m]) : (unsigned short)0;
}

__device__ __forceinline__ void cvtw_bd(const float* __restrict__ W, unsigned short* __restrict__ WT,
                                        int K, int M, int C, int Kp, int Kph, int i) {
    int m = i / Kp;
    int k = i - m * Kp;
    unsigned short v = 0;
    if (m < M) {
        int hm = m / C;
        int kk = k - hm * Kph;
        if (kk >= 0 && kk < K) v = f2bf(W[(long long)kk * M + m]);
    }
    WT[i] = v;
}

__device__ __forceinline__ void prep1(const float* __restrict__ W, const float* __restrict__ a_src,
                                      const float* __restrict__ a_dst, unsigned short* __restrict__ WT,
                                      int K, int M, int C, int Kp, int H, int b, int lane) {
    int k = b % Kp;
    int th = b / Kp;
    int t = th / H;
    int h = th - t * H;
    size_t orow = (size_t)(M + t * H + h) * Kp;
    if (k >= K) {
        if (lane == 0) WT[orow + k] = 0;
        return;
    }
    const float* a = t ? a_dst : a_src;
    int hoff = h * C;
    const float* wrow = W + (size_t)k * M + hoff;
    float acc = 0.f;
    for (int c = lane; c < C; c += 64) acc += wrow[c] * a[hoff + c];
    for (int off = 32; off > 0; off >>= 1) acc += __shfl_down(acc, off);
    if (lane == 0) WT[orow + k] = f2bf(acc);
}

__device__ __forceinline__ void prep1f(const float* __restrict__ W, const float* __restrict__ a_src,
                                       const float* __restrict__ a_dst, float* __restrict__ fout,
                                       int K, int M, int C, int Kp, int H, int b, int lane) {
    int k = b % Kp;
    int th = b / Kp;
    int t = th / H;
    int h = th - t * H;
    if (k >= K) {
        if (lane == 0) fout[(size_t)th * Kp + k] = 0.f;
        return;
    }
    const float* a = t ? a_dst : a_src;
    int hoff = h * C;
    const float* wrow = W + (size_t)k * M + hoff;
    float acc = 0.f;
    for (int c = lane; c < C; c += 64) acc += wrow[c] * a[hoff + c];
    for (int off = 32; off > 0; off >>= 1) acc += __shfl_down(acc, off);
    if (lane == 0) fout[(size_t)th * Kp + k] = acc;
}

// ==================== kernel A: count ∪ cvt_w ∪ prep_va ∪ cvt_x ====================

__global__ __launch_bounds__(256) void k_A(
    const int* __restrict__ mol_dst, const int* __restrict__ pro_dst, int* __restrict__ cnt,
    int N_MOL, int E_MOL, int ET, int nb1,
    const float* __restrict__ W1, const float* __restrict__ W2, const float* __restrict__ W3,
    const float* __restrict__ Wp1, const float* __restrict__ Wp2, const float* __restrict__ Wp3,
    unsigned short* __restrict__ wt1, unsigned short* __restrict__ wt2bd, unsigned short* __restrict__ wt3,
    unsigned short* __restrict__ wtp1, unsigned short* __restrict__ wtp2bd, unsigned short* __restrict__ wtp3,
    const float* __restrict__ as1, const float* __restrict__ ad1,
    const float* __restrict__ as2, const float* __restrict__ ad2,
    const float* __restrict__ as3, const float* __restrict__ ad3,
    const float* __restrict__ aps2, const float* __restrict__ apd2,
    const float* __restrict__ aps3, const float* __restrict__ apd3,
    float* __restrict__ va2f, float* __restrict__ vap2f,
    const float* __restrict__ mol_x, unsigned short* __restrict__ xb,
    const float* __restrict__ pro_x, unsigned short* __restrict__ xpp,
    long long totM, long long totP) {
    const int nb2 = 957;   // cvt_w: 244872/256
    const int nb3 = 508;   // prep: 2032 units / 4 waves
    int b = blockIdx.x;
    int tid = threadIdx.x;
    if (b < nb1) {
        int i0 = b * 1024 + tid;
#pragma unroll
        for (int k = 0; k < 4; k++) {
            int e = i0 + k * 256;
            if (e < ET) {
                int d = (e < E_MOL) ? mol_dst[e] : (N_MOL + pro_dst[e - E_MOL]);
                atomicAdd(&cnt[d], 1);
            }
        }
    } else if (b < nb1 + nb2) {
        int idx = (b - nb1) * 256 + tid;
        if (idx < 12480)        cvtw1(W1, wt1, 78, 156, 80, idx);
        else if (idx < 114880)  cvtw_bd(W2, wt2bd, 156, 312, 156, 320, 160, idx - 12480);
        else if (idx < 214720)  cvtw1(W3, wt3, 312, 312, 320, idx - 114880);
        else if (idx < 216040)  cvtw1(Wp1, wtp1, 33, 33, 40, idx - 214720);
        else if (idx < 226920)  cvtw_bd(Wp2, wtp2bd, 33, 132, 66, 80, 40, idx - 216040);
        else if (idx < 244872)  cvtw1(Wp3, wtp3, 132, 132, 136, idx - 226920);
    } else if (b < nb1 + nb2 + nb3) {
        int unit = (b - nb1 - nb2) * 4 + (tid >> 6);
        int lane = tid & 63;
        if (unit < 320)        prep1(W1, as1, ad1, wt1, 78, 156, 78, 80, 2, unit, lane);
        else if (unit < 960)   prep1f(W2, as2, ad2, va2f, 156, 312, 156, 160, 2, unit - 320, lane);
        else if (unit < 1600)  prep1(W3, as3, ad3, wt3, 312, 312, 312, 320, 1, unit - 960, lane);
        else if (unit < 1760)  prep1f(Wp2, aps2, apd2, vap2f, 33, 132, 66, 40, 2, unit - 1600, lane);
        else if (unit < 2032)  prep1(Wp3, aps3, apd3, wtp3, 132, 132, 132, 136, 1, unit - 1760, lane);
    } else {
        long long i0 = (long long)(b - nb1 - nb2 - nb3) * 1024 + tid;
#pragma unroll
        for (int k = 0; k < 4; k++) {
            long long idx = i0 + k * 256;
            if (idx < totM) {
                int n = (int)(idx / 80);
                int kk = (int)(idx - (long long)n * 80);
                xb[idx] = (kk < 78) ? f2bf(mol_x[(long long)n * 78 + kk]) : (unsigned short)0;
            } else if (idx < totM + totP) {
                long long i2 = idx - totM;
                int n = (int)(i2 / 40);
                int kk = (int)(i2 - (long long)n * 40);
                xpp[i2] = (kk < 33) ? f2bf(pro_x[(long long)n * 33 + kk]) : (unsigned short)0;
            }
        }
    }
}

// ==================== scans ====================

__global__ __launch_bounds__(256) void k_scan1(const int* __restrict__ cnt, int* __restrict__ incl,
                                               int* __restrict__ bsums, int n) {
    __shared__ int sm[256];
    int i = blockIdx.x * 256 + threadIdx.x;
    int v = (i < n) ? cnt[i] : 0;
    sm[threadIdx.x] = v;
    __syncthreads();
    for (int off = 1; off < 256; off <<= 1) {
        int t = (threadIdx.x >= off) ? sm[threadIdx.x - off] : 0;
        __syncthreads();
        sm[threadIdx.x] += t;
        __syncthreads();
    }
    if (i < n) incl[i] = sm[threadIdx.x];
    if (threadIdx.x == 255) bsums[blockIdx.x] = sm[255];
}

__global__ __launch_bounds__(1024) void k_scan2(int* __restrict__ bsums, int nb) {
    __shared__ int sm[1024];
    int v = (threadIdx.x < nb) ? bsums[threadIdx.x] : 0;
    sm[threadIdx.x] = v;
    __syncthreads();
    for (int off = 1; off < 1024; off <<= 1) {
        int t = (threadIdx.x >= off) ? sm[threadIdx.x - off] : 0;
        __syncthreads();
        sm[threadIdx.x] += t;
        __syncthreads();
    }
    if (threadIdx.x < nb) bsums[threadIdx.x] = sm[threadIdx.x] - v;
}

__global__ __launch_bounds__(256) void k_scan3_all(const int* __restrict__ incl, const int* __restrict__ cnt,
                                                   const int* __restrict__ boff,
                                                   int* __restrict__ mol_rowp, int* __restrict__ pro_rowp,
                                                   int* __restrict__ cur,
                                                   int N_MOL, int N_PRO, int E_MOL, int E_PRO) {
    int i = blockIdx.x * 256 + threadIdx.x;
    int NT = N_MOL + N_PRO;
    if (i < NT) {
        int ex = incl[i] - cnt[i] + boff[blockIdx.x];
        cur[i] = ex;
        if (i < N_MOL) mol_rowp[i] = ex;
        else pro_rowp[i - N_MOL] = ex - E_MOL;
    }
    if (i == 0) {
        mol_rowp[N_MOL] = E_MOL;
        pro_rowp[N_PRO] = E_PRO;
    }
}

// ==================== kernel B: scatter ∪ GEMM ∪ GEMM ====================

__global__ __launch_bounds__(256) void k_B(
    const int* __restrict__ msrc, const int* __restrict__ mdst,
    const int* __restrict__ psrc, const int* __restrict__ pdst,
    const float* __restrict__ pw, int* __restrict__ cur, int2* __restrict__ cpack,
    int N_MOL, int E_MOL, int ET, int nbs,
    const unsigned short* __restrict__ A1, const unsigned short* __restrict__ B1,
    unsigned short* __restrict__ C1, float* __restrict__ as1o, float* __restrict__ ad1o,
    const float* __restrict__ bias1, int relu1, int zpad1,
    int N1, int Kp1, int M1, int Mext1, int Mp1, int H1, int g1x, int nb1,
    const unsigned short* __restrict__ A2, const unsigned short* __restrict__ B2,
    unsigned short* __restrict__ C2, float* __restrict__ as2o, float* __restrict__ ad2o,
    const float* __restrict__ bias2, int relu2, int zpad2,
    int N2, int Kp2, int M2, int Mext2, int Mp2, int H2, int g2x) {
    int b = blockIdx.x;
    if (b < nbs) {
        int e = b * 256 + threadIdx.x;
        if (e < ET) {
            int s, d;
            int wbits = 0;
            if (e >= E_MOL) {
                int ep = e - E_MOL;
                s = psrc[ep];
                d = N_MOL + pdst[ep];
                wbits = __float_as_int(pw[ep]);
            } else {
                s = msrc[e];
                d = mdst[e];
            }
            int pos = atomicAdd(&cur[d], 1);
            int2 pk;
            pk.x = s;
            pk.y = wbits;
            cpack[pos] = pk;
        }
    } else if (b < nbs + nb1) {
        int bb = b - nbs;
        gemm_body(A1, B1, C1, as1o, ad1o, bias1, relu1, zpad1, N1, Kp1, M1, Mext1, Mp1, H1, bb % g1x, bb / g1x);
    } else {
        int bb = b - nbs - nb1;
        gemm_body(A2, B2, C2, as2o, ad2o, bias2, relu2, zpad2, N2, Kp2, M2, Mext2, Mp2, H2, bb % g2x, bb / g2x);
    }
}

// ==================== deg/dinv ====================

__global__ __launch_bounds__(256) void k_deg(const int* __restrict__ rowp, const int2* __restrict__ cpack,
                                             float* __restrict__ dinv, int N) {
    int n = blockIdx.x * 256 + threadIdx.x;
    if (n < N) {
        int b = rowp[n], e = rowp[n + 1];
        float s = 0.f;
        for (int p = b; p < e; p++) s += __int_as_float(cpack[p].y);
        dinv[n] = rsqrtf(s + 1.0f);
    }
}

// ==================== fused dispatches ====================

// F1: mol conv1 agg (NG=3, NEXTA->as2) ∪ pro gcn agg (NG=12, NEXTA->asp2)
__global__ __launch_bounds__(NPB * 64) void k_fuse1(
    const unsigned short* __restrict__ hb, const float* __restrict__ asm_, const float* __restrict__ adm_,
    const int* __restrict__ mrowp, const int2* __restrict__ mcp, const float* __restrict__ b1,
    unsigned short* __restrict__ x2m, const float* __restrict__ va2f,
    float* __restrict__ asm2, float* __restrict__ adm2, int Nm,
    const unsigned short* __restrict__ hbp, const float* __restrict__ dinv,
    const int* __restrict__ prowp, const int2* __restrict__ pcp, const float* __restrict__ bp1,
    unsigned short* __restrict__ x2p, const float* __restrict__ vap2f,
    float* __restrict__ asp2, float* __restrict__ adp2, int Np, int nb1) {
    int wave = threadIdx.x >> 6, lane = threadIdx.x & 63;
    int b = blockIdx.x;
    if (b < nb1) {
        int nbase = (b * NPB + wave) * 3;
        agg_gp<20, 3, 2, true, 1, false, true>(hb, asm_, adm_, nullptr, mrowp, mcp, b1,
                                               nullptr, x2m, va2f, 160, asm2, adm2,
                                               156, 160, 1, nbase, lane, Nm);
    } else {
        int nbase = ((b - nb1) * NPB + wave) * 12;
        agg_gp<5, 12, 1, false, 1, true, true>(hbp, nullptr, nullptr, dinv, prowp, pcp, bp1,
                                               nullptr, x2p, vap2f, 40, asp2, adp2,
                                               33, 40, 1, nbase, lane, Np);
    }
}

// F2: mol conv2 input-space agg (NG=3) ∪ pro conv2 input-space agg (NG=12)
__global__ __launch_bounds__(NPB * 64) void k_fuseN(
    const unsigned short* __restrict__ x2m, const float* __restrict__ asm2, const float* __restrict__ adm2,
    const int* __restrict__ mrowp, const int2* __restrict__ mcp, unsigned short* __restrict__ xa2m, int Nm,
    const unsigned short* __restrict__ x2p, const float* __restrict__ asp2, const float* __restrict__ adp2,
    const int* __restrict__ prowp, const int2* __restrict__ pcp, unsigned short* __restrict__ xa2p, int Np,
    int nb1) {
    int wave = threadIdx.x >> 6, lane = threadIdx.x & 63;
    int b = blockIdx.x;
    if (b < nb1) {
        int nbase = (b * NPB + wave) * 3;
        aggN_gp<20, 3>(x2m, asm2, adm2, mrowp, mcp, xa2m, nbase, lane, Nm);
    } else {
        int nbase = ((b - nb1) * NPB + wave) * 12;
        aggN_gp<5, 12>(x2p, asp2, adp2, prowp, pcp, xa2p, nbase, lane, Np);
    }
}

// F5: mol conv3 agg (NG=3, SWEEPS=2, fp32 out, no relu) ∪ pro conv3 agg (NG=3, fp32 out, relu)
__global__ __launch_bounds__(NPB * 64) void k_fuse5(
    const unsigned short* __restrict__ hb, const float* __restrict__ asm_, const float* __restrict__ adm_,
    const int* __restrict__ mrowp, const int2* __restrict__ mcp, const float* __restrict__ b3,
    float* __restrict__ out_mol, int Nm,
    const unsigned short* __restrict__ hbp, const float* __restrict__ asp_, const float* __restrict__ adp_,
    const int* __restrict__ prowp, const int2* __restrict__ pcp, const float* __restrict__ bp3,
    float* __restrict__ out_pro, int Np, int nb1) {
    int wave = threadIdx.x >> 6, lane = threadIdx.x & 63;
    int b = blockIdx.x;
    if (b < nb1) {
        int nbase = (b * NPB + wave) * 3;
        agg_gp<20, 3, 1, true, 2, false, false>(hb, asm_, adm_, nullptr, mrowp, mcp, b3,
                                                out_mol, nullptr, nullptr, 0, nullptr, nullptr,
                                                312, 320, 0, nbase, lane, Nm);
    } else {
        int nbase = ((b - nb1) * NPB + wave) * 3;
        agg_gp<17, 3, 1, true, 1, false, false>(hbp, asp_, adp_, nullptr, prowp, pcp, bp3,
                                                out_pro, nullptr, nullptr, 0, nullptr, nullptr,
                                                132, 136, 1, nbase, lane, Np);
    }
}

// ==================== launch ====================

extern "C" void kernel_launch(void* const* d_in, const int* in_sizes, int n_in,
                              void* d_out, int out_size, void* d_ws, size_t ws_size,
                              hipStream_t stream) {
    const int N_MOL = in_sizes[0] / 78;
    const int E_MOL = in_sizes[1] / 2;
    const int N_PRO = in_sizes[2] / 33;
    const int E_PRO = in_sizes[3] / 2;
    const int NT = N_MOL + N_PRO;
    const int ET = E_MOL + E_PRO;

    const float* mol_x = (const float*)d_in[0];
    const int* mol_ei = (const int*)d_in[1];
    const float* pro_x = (const float*)d_in[2];
    const int* pro_ei = (const int*)d_in[3];
    const float* pro_ew = (const float*)d_in[4];
    const float *W1 = (const float*)d_in[5], *as1 = (const float*)d_in[6], *ad1 = (const float*)d_in[7],
                *b1 = (const float*)d_in[8];
    const float *W2 = (const float*)d_in[9], *as2 = (const float*)d_in[10], *ad2 = (const float*)d_in[11],
                *b2 = (const float*)d_in[12];
    const float *W3 = (const float*)d_in[13], *as3 = (const float*)d_in[14], *ad3 = (const float*)d_in[15],
                *b3 = (const float*)d_in[16];
    const float *Wp1 = (const float*)d_in[17], *bp1 = (const float*)d_in[18];
    const float *Wp2 = (const float*)d_in[19], *aps2 = (const float*)d_in[20], *apd2 = (const float*)d_in[21],
                *bp2 = (const float*)d_in[22];
    const float *Wp3 = (const float*)d_in[23], *aps3 = (const float*)d_in[24], *apd3 = (const float*)d_in[25],
                *bp3 = (const float*)d_in[26];

    float* out_mol = (float*)d_out;
    float* out_pro = (float*)d_out + (size_t)N_MOL * 312;

    // ---------- d_out as scratch for buffers dead before F5 (passed in R7) ----------
    char* ob = (char*)d_out;
    size_t o_xa2m = 0;
    size_t o_xa2p = o_xa2m + (size_t)N_MOL * 320 * 2;                 // 32.0 MB
    size_t o_xb0  = o_xa2p + (size_t)N_PRO * 80 * 2;                  // 48.0 MB
    size_t o_xp0  = o_xb0 + (size_t)N_MOL * 80 * 2;                   // 56.0 MB
    size_t o_xpp  = o_xp0 + (size_t)N_PRO * 40 * 2;                   // 64.0 MB (+27.2 = 91.2 <= 115.2)
    unsigned short* xa2m = (unsigned short*)(ob + o_xa2m);
    unsigned short* xa2p = (unsigned short*)(ob + o_xa2p);
    unsigned short* xb0  = (unsigned short*)(ob + o_xb0);
    unsigned short* xp0  = (unsigned short*)(ob + o_xp0);
    unsigned short* xpp  = (unsigned short*)(ob + o_xpp);

    // ---------- workspace (~107 MB) ----------
    char* p = (char*)d_ws;
    auto alloc = [&](size_t bytes) -> void* {
        void* r = (void*)p;
        p += (bytes + 255) & ~(size_t)255;
        return r;
    };
    int* cnt_all  = (int*)alloc((size_t)NT * 4);
    int* incl     = (int*)alloc((size_t)NT * 4);
    int* cur_all  = (int*)alloc((size_t)NT * 4);
    int* bsums    = (int*)alloc(1024 * 4);
    int* mol_rowp = (int*)alloc((size_t)(N_MOL + 1) * 4);
    int* pro_rowp = (int*)alloc((size_t)(N_PRO + 1) * 4);
    int2* cpack   = (int2*)alloc((size_t)ET * 8);
    float* dinv   = (float*)alloc((size_t)N_PRO * 4);
    float* asb_m  = (float*)alloc((size_t)N_MOL * 2 * 4);
    float* adb_m  = (float*)alloc((size_t)N_MOL * 2 * 4);
    float* asb_m2 = (float*)alloc((size_t)N_MOL * 2 * 4);
    float* adb_m2 = (float*)alloc((size_t)N_MOL * 2 * 4);
    float* asb_p  = (float*)alloc((size_t)N_PRO * 2 * 4);
    float* adb_p  = (float*)alloc((size_t)N_PRO * 2 * 4);
    float* asb_p2 = (float*)alloc((size_t)N_PRO * 2 * 4);
    float* adb_p2 = (float*)alloc((size_t)N_PRO * 2 * 4);
    float* va2f   = (float*)alloc((size_t)4 * 160 * 4);
    float* vap2f  = (float*)alloc((size_t)4 * 40 * 4);
    unsigned short* bufA = (unsigned short*)alloc((size_t)N_MOL * 320 * 2);
    unsigned short* bufB = (unsigned short*)alloc((size_t)N_MOL * 320 * 2);
    unsigned short* bufC = (unsigned short*)alloc((size_t)N_PRO * 136 * 2);
    unsigned short* wt1    = (unsigned short*)alloc((size_t)160 * 80 * 2);
    unsigned short* wt2bd  = (unsigned short*)alloc((size_t)320 * 320 * 2);
    unsigned short* wt3    = (unsigned short*)alloc((size_t)320 * 320 * 2);
    unsigned short* wtp1   = (unsigned short*)alloc((size_t)40 * 40 * 2);
    unsigned short* wtp2bd = (unsigned short*)alloc((size_t)136 * 80 * 2);
    unsigned short* wtp3   = (unsigned short*)alloc((size_t)136 * 136 * 2);
    (void)ws_size;

    unsigned short* hb1  = bufA;
    unsigned short* x3m  = bufA;
    unsigned short* x2m  = bufB;
    unsigned short* x2p  = bufB + (size_t)N_MOL * 160;
    unsigned short* hb3  = bufB;
    unsigned short* hbp1 = bufC;
    unsigned short* hbp3 = bufC;

    int2* mol_cp = cpack;
    int2* pro_cp = cpack + E_MOL;

    const int* mol_src = mol_ei;
    const int* mol_dst = mol_ei + E_MOL;
    const int* pro_src = pro_ei;
    const int* pro_dst = pro_ei + E_PRO;

    const long long totM = (long long)N_MOL * 80;
    const long long totP = (long long)N_PRO * 40;

    // ---- A ----
    hipMemsetAsync(cnt_all, 0, (size_t)NT * 4, stream);
    int nbCnt = (ET + 1023) / 1024;
    int nbCvx = (int)((totM + totP + 1023) / 1024);
    int gridA = nbCnt + 957 + 508 + nbCvx;
    k_A<<<gridA, 256, 0, stream>>>(mol_dst, pro_dst, cnt_all, N_MOL, E_MOL, ET, nbCnt,
                                   W1, W2, W3, Wp1, Wp2, Wp3, wt1, wt2bd, wt3, wtp1, wtp2bd, wtp3,
                                   as1, ad1, as2, ad2, as3, ad3, aps2, apd2, aps3, apd3,
                                   va2f, vap2f, mol_x, xb0, pro_x, xp0, totM, totP);

    // ---- scans ----
    int nbT = (NT + 255) / 256;
    k_scan1<<<nbT, 256, 0, stream>>>(cnt_all, incl, bsums, NT);
    k_scan2<<<1, 1024, 0, stream>>>(bsums, nbT);
    k_scan3_all<<<nbT, 256, 0, stream>>>(incl, cnt_all, bsums, mol_rowp, pro_rowp, cur_all,
                                         N_MOL, N_PRO, E_MOL, E_PRO);

    int gyM = (N_MOL + TBM - 1) / TBM;
    int gyP = (N_PRO + TBM - 1) / TBM;

    // ---- B1: scatter ∪ GEMM1m (alpha rows) ∪ GEMMp1 (plain) ----
    {
        int nbs = (ET + 255) / 256;
        int g1x = 2;                       // Mext=160
        int nb1 = g1x * gyM;
        int g2x = 1;                       // Mext=33
        k_B<<<nbs + nb1 + g2x * gyP, 256, 0, stream>>>(
            mol_src, mol_dst, pro_src, pro_dst, pro_ew, cur_all, cpack, N_MOL, E_MOL, ET, nbs,
            xb0, wt1, hb1, asb_m, adb_m, nullptr, 0, 0, N_MOL, 80, 156, 160, 160, 2, g1x, nb1,
            xp0, wtp1, hbp1, nullptr, nullptr, nullptr, 0, 0, N_PRO, 40, 33, 33, 40, 0, g2x);
    }

    k_deg<<<(N_PRO + 255) / 256, 256, 0, stream>>>(pro_rowp, pro_cp, dinv, N_PRO);

    // ---- F1: agg1m (->x2m, as2) ∪ gcn agg (->x2p, asp2) ----
    {
        int nb1 = (N_MOL + NPB * 3 - 1) / (NPB * 3);
        int nb2 = (N_PRO + NPB * 12 - 1) / (NPB * 12);
        k_fuse1<<<nb1 + nb2, NPB * 64, 0, stream>>>(hb1, asb_m, adb_m, mol_rowp, mol_cp, b1,
                                                    x2m, va2f, asb_m2, adb_m2, N_MOL,
                                                    hbp1, dinv, pro_rowp, pro_cp, bp1,
                                                    x2p, vap2f, asb_p2, adb_p2, N_PRO, nb1);
    }

    // ---- F2: input-space aggs (x2m -> xa2m) ∪ (x2p -> xa2p) ----
    {
        int nb1 = (N_MOL + NPB * 3 - 1) / (NPB * 3);
        int nb2 = (N_PRO + NPB * 12 - 1) / (NPB * 12);
        k_fuseN<<<nb1 + nb2, NPB * 64, 0, stream>>>(x2m, asb_m2, adb_m2, mol_rowp, mol_cp, xa2m, N_MOL,
                                                    x2p, asb_p2, adb_p2, pro_rowp, pro_cp, xa2p, N_PRO, nb1);
    }

    // ---- F3: block-diag GEMMs: xa2m@wt2bd -> x3m (+b2,relu) ∪ xa2p@wtp2bd -> xpp (+bp2,relu) ----
    {
        int g1x = 3;                       // Mext=320
        int nb1 = g1x * gyM;
        int g2x = 2;                       // Mext=136
        k_B<<<nb1 + g2x * gyP, 256, 0, stream>>>(
            nullptr, nullptr, nullptr, nullptr, nullptr, nullptr, nullptr, N_MOL, E_MOL, ET, 0,
            xa2m, wt2bd, x3m, nullptr, nullptr, b2, 1, 320, N_MOL, 320, 312, 320, 320, 0, g1x, nb1,
            xa2p, wtp2bd, xpp, nullptr, nullptr, bp2, 1, 136, N_PRO, 80, 132, 136, 136, 0, g2x);
    }

    // ---- F4: GEMM3m (alpha) ∪ GEMMp3 (alpha) ----
    {
        int g1x = 3;                       // Mext=314
        int nb1 = g1x * gyM;
        int g2x = 2;                       // Mext=134
        k_B<<<nb1 + g2x * gyP, 256, 0, stream>>>(
            nullptr, nullptr, nullptr, nullptr, nullptr, nullptr, nullptr, N_MOL, E_MOL, ET, 0,
            x3m, wt3, hb3, asb_m, adb_m, nullptr, 0, 0, N_MOL, 320, 312, 314, 320, 1, g1x, nb1,
            xpp, wtp3, hbp3, asb_p, adb_p, nullptr, 0, 0, N_PRO, 136, 132, 134, 136, 1, g2x);
    }

    // ---- F5: final aggs -> outputs ----
    {
        int nb1 = (N_MOL + NPB * 3 - 1) / (NPB * 3);
        int nb2 = (N_PRO + NPB * 3 - 1) / (NPB * 3);
        k_fuse5<<<nb1 + nb2, NPB * 64, 0, stream>>>(hb3, asb_m, adb_m, mol_rowp, mol_cp, b3, out_mol, N_MOL,
                                                    hbp3, asb_p, adb_p, pro_rowp, pro_cp, bp3, out_pro, N_PRO, nb1);
    }
}

// Round 9
// 691.827 us; speedup vs baseline: 1.2180x; 1.0221x over previous
//
#include <hip/hip_runtime.h>
#include <cstdint>
#include <cstddef>

#define WAVE 64
#define NPB 4   // waves per aggregation block

#define TBM 128
#define TBN 128
#define TBK 32
#define LDK 40

typedef short s16x8 __attribute__((ext_vector_type(8)));
typedef float f32x4 __attribute__((ext_vector_type(4)));

__device__ __forceinline__ unsigned short f2bf(float f) {
    unsigned int u = __float_as_uint(f);
    unsigned int r = (u + 0x7fffu + ((u >> 16) & 1u)) >> 16;
    return (unsigned short)r;
}
__device__ __forceinline__ float bf2f_lo(unsigned int v) { return __uint_as_float(v << 16); }
__device__ __forceinline__ float bf2f_hi(unsigned int v) { return __uint_as_float(v & 0xffff0000u); }
__device__ __forceinline__ float lrelu02(float e) { return (e > 0.f) ? e : 0.2f * e; }

// ==================== GEMM body ====================

__device__ __forceinline__ void gemm_body(const unsigned short* __restrict__ A,
                                          const unsigned short* __restrict__ BT,
                                          unsigned short* __restrict__ Cbf,
                                          float* __restrict__ asb, float* __restrict__ adb,
                                          const float* __restrict__ bias, int relu, int zpadTo,
                                          int N, int Kp, int M, int Mext, int Mp, int H,
                                          int bx, int by) {
    __shared__ __align__(16) unsigned short As[TBM * LDK];
    __shared__ __align__(16) unsigned short Bs[TBN * LDK];
    int tid = threadIdx.x;
    int wave = tid >> 6;
    int lane = tid & 63;
    int rowBase = by * TBM;
    int colBase = bx * TBN;
    int wm = (wave & 1) * 64;
    int wn = (wave >> 1) * 64;
    int l15 = lane & 15;
    int quad = lane >> 4;

    f32x4 acc[4][4];
    f32x4 z4 = {0.f, 0.f, 0.f, 0.f};
#pragma unroll
    for (int i = 0; i < 4; i++)
#pragma unroll
        for (int j = 0; j < 4; j++) acc[i][j] = z4;

    int srow = tid >> 2;
    int skg = tid & 3;
    const uint4 zero16 = {0u, 0u, 0u, 0u};

    for (int k0 = 0; k0 < Kp; k0 += TBK) {
#pragma unroll
        for (int half = 0; half < 2; half++) {
            int row = srow + half * 64;
            int gk = k0 + skg * 8;
            bool kok = (gk < Kp);
            {
                int gr = rowBase + row;
                uint4 v = zero16;
                if (kok && gr < N) v = *(const uint4*)(A + (size_t)gr * Kp + gk);
                *(uint4*)(As + row * LDK + skg * 8) = v;
            }
            {
                int gc = colBase + row;
                uint4 v = zero16;
                if (kok && gc < Mext) v = *(const uint4*)(BT + (size_t)gc * Kp + gk);
                *(uint4*)(Bs + row * LDK + skg * 8) = v;
            }
        }
        __syncthreads();

        s16x8 af[4], bfr[4];
#pragma unroll
        for (int mt = 0; mt < 4; mt++)
            af[mt] = *(const s16x8*)(As + (wm + mt * 16 + l15) * LDK + quad * 8);
#pragma unroll
        for (int nt = 0; nt < 4; nt++)
            bfr[nt] = *(const s16x8*)(Bs + (wn + nt * 16 + l15) * LDK + quad * 8);
#pragma unroll
        for (int mt = 0; mt < 4; mt++)
#pragma unroll
            for (int nt = 0; nt < 4; nt++)
                acc[mt][nt] = __builtin_amdgcn_mfma_f32_16x16x32_bf16(af[mt], bfr[nt], acc[mt][nt], 0, 0, 0);
        __syncthreads();
    }

#pragma unroll
    for (int mt = 0; mt < 4; mt++) {
#pragma unroll
        for (int r = 0; r < 4; r++) {
            int row = rowBase + wm + mt * 16 + quad * 4 + r;
            if (row < N) {
#pragma unroll
                for (int nt = 0; nt < 4; nt++) {
                    int col = colBase + wn + nt * 16 + l15;
                    float v = acc[mt][nt][r];
                    if (col < M) {
                        float v2 = v;
                        if (bias != nullptr) {
                            v2 += bias[col];
                            if (relu) v2 = fmaxf(v2, 0.f);
                        }
                        Cbf[(size_t)row * Mp + col] = f2bf(v2);
                    } else if (col < zpadTo) {
                        Cbf[(size_t)row * Mp + col] = 0;
                    } else if (asb != nullptr && col < M + 2 * H) {
                        int t = col - M;
                        if (t < H) asb[(size_t)row * H + t] = v;
                        else adb[(size_t)row * H + (t - H)] = v;
                    }
                }
            }
        }
    }
}

// ==================== group-per-node aggregation (h-space) ====================

template <int SLOTS, int NG, int H, bool SM, int SWEEPS, bool GCN, bool NEXTA>
__device__ __forceinline__ void agg_gp(const unsigned short* __restrict__ hfeat,
                                       const float* __restrict__ as_, const float* __restrict__ ad_,
                                       const float* __restrict__ dinv,
                                       const int* __restrict__ rowp, const int2* __restrict__ cpack,
                                       const float* __restrict__ bias,
                                       float* __restrict__ out_f, unsigned short* __restrict__ out_bf,
                                       const float* __restrict__ vanf, int vald,
                                       float* __restrict__ asn, float* __restrict__ adn_o,
                                       int HC, int ldo, int relu, int nbase, int lane, int N) {
    constexpr int ROWB = SWEEPS * SLOTS * 16;
    int g = lane / SLOTS;
    int slot = lane - g * SLOTS;
    int n = nbase + g;
    if (g >= NG || n >= N) return;
    int C = HC / H;
    int beg = rowp[n], end = rowp[n + 1];

    float adn[H], msub[H];
    float di = 0.f, sfw;
    if (GCN) {
        di = dinv[n];
        sfw = di * di;
    } else {
#pragma unroll
        for (int h = 0; h < H; h++) {
            adn[h] = ad_[(size_t)n * H + h];
            msub[h] = lrelu02(as_[(size_t)n * H + h] + adn[h]);
        }
        sfw = 1.f;
    }

    int ch0[SWEEPS];
    bool h1q[SWEEPS][4];
#pragma unroll
    for (int sw = 0; sw < SWEEPS; sw++) {
        ch0[sw] = (sw * SLOTS + slot) * 8;
#pragma unroll
        for (int q = 0; q < 4; q++) h1q[sw][q] = (H == 2) && ((ch0[sw] + 2 * q) >= C);
    }

    float accx[SWEEPS][4], accy[SWEEPS][4];
#pragma unroll
    for (int sw = 0; sw < SWEEPS; sw++) {
        uint4 v = *(const uint4*)((const char*)hfeat + (size_t)n * ROWB + (sw * SLOTS + slot) * 16);
        unsigned int vv[4] = {v.x, v.y, v.z, v.w};
#pragma unroll
        for (int q = 0; q < 4; q++) { accx[sw][q] = sfw * bf2f_lo(vv[q]); accy[sw][q] = sfw * bf2f_hi(vv[q]); }
    }

    float wsum[H];
#pragma unroll
    for (int h = 0; h < H; h++) wsum[h] = 0.f;

    int p = beg;
    for (; p + 1 < end; p += 2) {
        int2 pk0 = cpack[p];
        int2 pk1 = cpack[p + 1];
        int s0 = pk0.x, s1 = pk1.x;
        float w0[H], w1[H];
        if (GCN) {
            w0[0] = dinv[s0] * __int_as_float(pk0.y) * di;
            w1[0] = dinv[s1] * __int_as_float(pk1.y) * di;
        } else {
#pragma unroll
            for (int h = 0; h < H; h++) {
                w0[h] = __expf(lrelu02(as_[(size_t)s0 * H + h] + adn[h]) - msub[h]);
                w1[h] = __expf(lrelu02(as_[(size_t)s1 * H + h] + adn[h]) - msub[h]);
            }
        }
        if (SM) {
#pragma unroll
            for (int h = 0; h < H; h++) wsum[h] += w0[h] + w1[h];
        }
        uint4 v0[SWEEPS], v1[SWEEPS];
#pragma unroll
        for (int sw = 0; sw < SWEEPS; sw++)
            v0[sw] = *(const uint4*)((const char*)hfeat + (size_t)s0 * ROWB + (sw * SLOTS + slot) * 16);
#pragma unroll
        for (int sw = 0; sw < SWEEPS; sw++)
            v1[sw] = *(const uint4*)((const char*)hfeat + (size_t)s1 * ROWB + (sw * SLOTS + slot) * 16);
#pragma unroll
        for (int sw = 0; sw < SWEEPS; sw++) {
            unsigned int a0[4] = {v0[sw].x, v0[sw].y, v0[sw].z, v0[sw].w};
            unsigned int a1[4] = {v1[sw].x, v1[sw].y, v1[sw].z, v1[sw].w};
#pragma unroll
            for (int q = 0; q < 4; q++) {
                float wq0 = (H == 2) ? (h1q[sw][q] ? w0[1] : w0[0]) : w0[0];
                float wq1 = (H == 2) ? (h1q[sw][q] ? w1[1] : w1[0]) : w1[0];
                accx[sw][q] += wq0 * bf2f_lo(a0[q]) + wq1 * bf2f_lo(a1[q]);
                accy[sw][q] += wq0 * bf2f_hi(a0[q]) + wq1 * bf2f_hi(a1[q]);
            }
        }
    }
    if (p < end) {
        int2 pk0 = cpack[p];
        int s0 = pk0.x;
        float w0[H];
        if (GCN) {
            w0[0] = dinv[s0] * __int_as_float(pk0.y) * di;
        } else {
#pragma unroll
            for (int h = 0; h < H; h++)
                w0[h] = __expf(lrelu02(as_[(size_t)s0 * H + h] + adn[h]) - msub[h]);
        }
        if (SM) {
#pragma unroll
            for (int h = 0; h < H; h++) wsum[h] += w0[h];
        }
        uint4 v0[SWEEPS];
#pragma unroll
        for (int sw = 0; sw < SWEEPS; sw++)
            v0[sw] = *(const uint4*)((const char*)hfeat + (size_t)s0 * ROWB + (sw * SLOTS + slot) * 16);
#pragma unroll
        for (int sw = 0; sw < SWEEPS; sw++) {
            unsigned int a0[4] = {v0[sw].x, v0[sw].y, v0[sw].z, v0[sw].w};
#pragma unroll
            for (int q = 0; q < 4; q++) {
                float wq0 = (H == 2) ? (h1q[sw][q] ? w0[1] : w0[0]) : w0[0];
                accx[sw][q] += wq0 * bf2f_lo(a0[q]);
                accy[sw][q] += wq0 * bf2f_hi(a0[q]);
            }
        }
    }

    float rs[H];
    if (SM) {
#pragma unroll
        for (int h = 0; h < H; h++) rs[h] = 1.f / (1.f + wsum[h] + 1e-16f);
    } else {
#pragma unroll
        for (int h = 0; h < H; h++) rs[h] = 1.f;
    }

    float ps[4] = {0.f, 0.f, 0.f, 0.f};
#pragma unroll
    for (int sw = 0; sw < SWEEPS; sw++) {
        float o[8];
#pragma unroll
        for (int q = 0; q < 4; q++) {
            float r = (H == 2) ? (h1q[sw][q] ? rs[1] : rs[0]) : rs[0];
            int c0 = ch0[sw] + 2 * q;
            float b0 = (c0 < HC) ? bias[c0] : 0.f;
            float b1v = (c0 + 1 < HC) ? bias[c0 + 1] : 0.f;
            float o0 = accx[sw][q] * r + b0;
            float o1 = accy[sw][q] * r + b1v;
            if (relu) { o0 = fmaxf(o0, 0.f); o1 = fmaxf(o1, 0.f); }
            if (c0 >= HC) o0 = 0.f;
            if (c0 + 1 >= HC) o1 = 0.f;
            o[2 * q] = o0;
            o[2 * q + 1] = o1;
        }
        if (NEXTA) {
#pragma unroll
            for (int j = 0; j < 8; j++) {
                int c = ch0[sw] + j;
#pragma unroll
                for (int th = 0; th < 4; th++) ps[th] += o[j] * vanf[th * vald + c];
            }
        }
        if (out_bf) {
            uint4 pk;
            unsigned* pp = (unsigned*)&pk;
#pragma unroll
            for (int q = 0; q < 4; q++)
                pp[q] = (unsigned)f2bf(o[2 * q]) | ((unsigned)f2bf(o[2 * q + 1]) << 16);
            *(uint4*)((char*)out_bf + (size_t)n * ((size_t)ldo * 2) + (sw * SLOTS + slot) * 16) = pk;
        } else {
#pragma unroll
            for (int half = 0; half < 2; half++) {
                int c0 = ch0[sw] + half * 4;
                if (c0 < HC) {
                    float4 f4 = make_float4(o[half * 4], o[half * 4 + 1], o[half * 4 + 2], o[half * 4 + 3]);
                    *(float4*)(out_f + (size_t)n * HC + c0) = f4;
                }
            }
        }
    }
    if (NEXTA) {
        constexpr int P = SLOTS >= 32 ? 32 : SLOTS >= 16 ? 16 : SLOTS >= 8 ? 8 : SLOTS >= 4 ? 4 : SLOTS >= 2 ? 2 : 1;
        if (P < SLOTS) {
#pragma unroll
            for (int th = 0; th < 4; th++) {
                float t = __shfl_down(ps[th], P);
                if (slot + P < SLOTS) ps[th] += t;
            }
        }
#pragma unroll
        for (int off = P >> 1; off > 0; off >>= 1) {
#pragma unroll
            for (int th = 0; th < 4; th++) {
                float t = __shfl_down(ps[th], off);
                if (slot + off < P) ps[th] += t;
            }
        }
        if (slot == 0) {
            asn[(size_t)n * 2 + 0] = ps[0];
            asn[(size_t)n * 2 + 1] = ps[1];
            adn_o[(size_t)n * 2 + 0] = ps[2];
            adn_o[(size_t)n * 2 + 1] = ps[3];
        }
    }
}

// ==================== group-per-node input-space aggregation (H=2) ====================

template <int SLOTS, int NG>
__device__ __forceinline__ void aggN_gp(const unsigned short* __restrict__ x,
                                        const float* __restrict__ as_, const float* __restrict__ ad_,
                                        const int* __restrict__ rowp, const int2* __restrict__ cpack,
                                        unsigned short* __restrict__ A2, int nbase, int lane, int N) {
    constexpr int ROWB = SLOTS * 16;
    int g = lane / SLOTS;
    int slot = lane - g * SLOTS;
    int n = nbase + g;
    if (g >= NG || n >= N) return;
    int beg = rowp[n], end = rowp[n + 1];

    float adn[2], msub[2];
#pragma unroll
    for (int h = 0; h < 2; h++) {
        adn[h] = ad_[(size_t)n * 2 + h];
        msub[h] = lrelu02(as_[(size_t)n * 2 + h] + adn[h]);
    }

    float ax[2][4], ay[2][4];
    {
        uint4 v = *(const uint4*)((const char*)x + (size_t)n * ROWB + slot * 16);
        unsigned int vv[4] = {v.x, v.y, v.z, v.w};
#pragma unroll
        for (int q = 0; q < 4; q++) {
            float lo = bf2f_lo(vv[q]), hi = bf2f_hi(vv[q]);
            ax[0][q] = lo; ax[1][q] = lo;
            ay[0][q] = hi; ay[1][q] = hi;
        }
    }
    float wsum[2] = {0.f, 0.f};

    int p = beg;
    for (; p + 1 < end; p += 2) {
        int s0 = cpack[p].x;
        int s1 = cpack[p + 1].x;
        float w0[2], w1[2];
#pragma unroll
        for (int h = 0; h < 2; h++) {
            w0[h] = __expf(lrelu02(as_[(size_t)s0 * 2 + h] + adn[h]) - msub[h]);
            w1[h] = __expf(lrelu02(as_[(size_t)s1 * 2 + h] + adn[h]) - msub[h]);
        }
        wsum[0] += w0[0] + w1[0];
        wsum[1] += w0[1] + w1[1];
        uint4 v0 = *(const uint4*)((const char*)x + (size_t)s0 * ROWB + slot * 16);
        uint4 v1 = *(const uint4*)((const char*)x + (size_t)s1 * ROWB + slot * 16);
        unsigned int a0[4] = {v0.x, v0.y, v0.z, v0.w};
        unsigned int a1[4] = {v1.x, v1.y, v1.z, v1.w};
#pragma unroll
        for (int q = 0; q < 4; q++) {
            float lo0 = bf2f_lo(a0[q]), hi0 = bf2f_hi(a0[q]);
            float lo1 = bf2f_lo(a1[q]), hi1 = bf2f_hi(a1[q]);
            ax[0][q] += w0[0] * lo0 + w1[0] * lo1;
            ax[1][q] += w0[1] * lo0 + w1[1] * lo1;
            ay[0][q] += w0[0] * hi0 + w1[0] * hi1;
            ay[1][q] += w0[1] * hi0 + w1[1] * hi1;
        }
    }
    if (p < end) {
        int s0 = cpack[p].x;
        float w0[2];
#pragma unroll
        for (int h = 0; h < 2; h++)
            w0[h] = __expf(lrelu02(as_[(size_t)s0 * 2 + h] + adn[h]) - msub[h]);
        wsum[0] += w0[0];
        wsum[1] += w0[1];
        uint4 v0 = *(const uint4*)((const char*)x + (size_t)s0 * ROWB + slot * 16);
        unsigned int a0[4] = {v0.x, v0.y, v0.z, v0.w};
#pragma unroll
        for (int q = 0; q < 4; q++) {
            float lo0 = bf2f_lo(a0[q]), hi0 = bf2f_hi(a0[q]);
            ax[0][q] += w0[0] * lo0;
            ax[1][q] += w0[1] * lo0;
            ay[0][q] += w0[0] * hi0;
            ay[1][q] += w0[1] * hi0;
        }
    }

    float rs[2];
#pragma unroll
    for (int h = 0; h < 2; h++) rs[h] = 1.f / (1.f + wsum[h] + 1e-16f);

#pragma unroll
    for (int h = 0; h < 2; h++) {
        uint4 pk;
        unsigned* pp = (unsigned*)&pk;
#pragma unroll
        for (int q = 0; q < 4; q++) {
            float o0 = ax[h][q] * rs[h];
            float o1 = ay[h][q] * rs[h];
            pp[q] = (unsigned)f2bf(o0) | ((unsigned)f2bf(o1) << 16);
        }
        *(uint4*)((char*)A2 + (size_t)n * (2 * ROWB) + h * ROWB + slot * 16) = pk;
    }
}

// ==================== helpers for kernel A ====================

__device__ __forceinline__ void cvtw1(const float* __restrict__ W, unsigned short* __restrict__ WT,
                                      int K, int M, int Kp, int i) {
    int m = i / Kp;
    int k = i - m * Kp;
    WT[i] = (k < K) ? f2bf(W[(long long)k * M + m]) : (unsigned short)0;
}

__device__ __forceinline__ void cvtw_bd(const float* __restrict__ W, unsigned short* __restrict__ WT,
                                        int K, int M, int C, int Kp, int Kph, int i) {
    int m = i / Kp;
    int k = i - m * Kp;
    unsigned short v = 0;
    if (m < M) {
        int hm = m / C;
        int kk = k - hm * Kph;
        if (kk >= 0 && kk < K) v = f2bf(W[(long long)kk * M + m]);
    }
    WT[i] = v;
}

__device__ __forceinline__ void prep1(const float* __restrict__ W, const float* __restrict__ a_src,
                                      const float* __restrict__ a_dst, unsigned short* __restrict__ WT,
                                      int K, int M, int C, int Kp, int H, int b, int lane) {
    int k = b % Kp;
    int th = b / Kp;
    int t = th / H;
    int h = th - t * H;
    size_t orow = (size_t)(M + t * H + h) * Kp;
    if (k >= K) {
        if (lane == 0) WT[orow + k] = 0;
        return;
    }
    const float* a = t ? a_dst : a_src;
    int hoff = h * C;
    const float* wrow = W + (size_t)k * M + hoff;
    float acc = 0.f;
    for (int c = lane; c < C; c += 64) acc += wrow[c] * a[hoff + c];
    for (int off = 32; off > 0; off >>= 1) acc += __shfl_down(acc, off);
    if (lane == 0) WT[orow + k] = f2bf(acc);
}

__device__ __forceinline__ void prep1f(const float* __restrict__ W, const float* __restrict__ a_src,
                                       const float* __restrict__ a_dst, float* __restrict__ fout,
                                       int K, int M, int C, int Kp, int H, int b, int lane) {
    int k = b % Kp;
    int th = b / Kp;
    int t = th / H;
    int h = th - t * H;
    if (k >= K) {
        if (lane == 0) fout[(size_t)th * Kp + k] = 0.f;
        return;
    }
    const float* a = t ? a_dst : a_src;
    int hoff = h * C;
    const float* wrow = W + (size_t)k * M + hoff;
    float acc = 0.f;
    for (int c = lane; c < C; c += 64) acc += wrow[c] * a[hoff + c];
    for (int off = 32; off > 0; off >>= 1) acc += __shfl_down(acc, off);
    if (lane == 0) fout[(size_t)th * Kp + k] = acc;
}

// ==================== kernel A: count ∪ bucket-hist ∪ cvt_w ∪ prep_va ∪ cvt_x ====================

__global__ __launch_bounds__(256) void k_A(
    const int* __restrict__ mol_dst, const int* __restrict__ pro_dst, int* __restrict__ cnt,
    int N_MOL, int E_MOL, int ET, int nb1,
    int* __restrict__ hist, int NBLK, int NBUK, int SH, int ROUNDS,
    const float* __restrict__ W1, const float* __restrict__ W2, const float* __restrict__ W3,
    const float* __restrict__ Wp1, const float* __restrict__ Wp2, const float* __restrict__ Wp3,
    unsigned short* __restrict__ wt1, unsigned short* __restrict__ wt2bd, unsigned short* __restrict__ wt3,
    unsigned short* __restrict__ wtp1, unsigned short* __restrict__ wtp2bd, unsigned short* __restrict__ wtp3,
    const float* __restrict__ as1, const float* __restrict__ ad1,
    const float* __restrict__ as2, const float* __restrict__ ad2,
    const float* __restrict__ as3, const float* __restrict__ ad3,
    const float* __restrict__ aps2, const float* __restrict__ apd2,
    const float* __restrict__ aps3, const float* __restrict__ apd3,
    float* __restrict__ va2f, float* __restrict__ vap2f,
    const float* __restrict__ mol_x, unsigned short* __restrict__ xb,
    const float* __restrict__ pro_x, unsigned short* __restrict__ xpp,
    long long totM, long long totP) {
    const int nb2 = 957;   // cvt_w: 244872/256
    const int nb3 = 508;   // prep: 2032 units / 4 waves
    int b = blockIdx.x;
    int tid = threadIdx.x;
    __shared__ int lhist[256];
    if (b < nb1) {
        int i0 = b * 1024 + tid;
#pragma unroll
        for (int k = 0; k < 4; k++) {
            int e = i0 + k * 256;
            if (e < ET) {
                int d = (e < E_MOL) ? mol_dst[e] : (N_MOL + pro_dst[e - E_MOL]);
                atomicAdd(&cnt[d], 1);
            }
        }
    } else if (b < nb1 + NBLK) {
        // bucket histogram per edge-block (same block<->edge mapping as pass1)
        int eb = b - nb1;
        lhist[tid] = 0;
        __syncthreads();
        int base = eb * (ROUNDS * 256);
        for (int r = 0; r < ROUNDS; r++) {
            int e = base + r * 256 + tid;
            if (e < ET) {
                int d = (e < E_MOL) ? mol_dst[e] : (N_MOL + pro_dst[e - E_MOL]);
                atomicAdd(&lhist[d >> SH], 1);
            }
        }
        __syncthreads();
        if (tid < NBUK) hist[tid * NBLK + eb] = lhist[tid];
    } else if (b < nb1 + NBLK + nb2) {
        int idx = (b - nb1 - NBLK) * 256 + tid;
        if (idx < 12480)        cvtw1(W1, wt1, 78, 156, 80, idx);
        else if (idx < 114880)  cvtw_bd(W2, wt2bd, 156, 312, 156, 320, 160, idx - 12480);
        else if (idx < 214720)  cvtw1(W3, wt3, 312, 312, 320, idx - 114880);
        else if (idx < 216040)  cvtw1(Wp1, wtp1, 33, 33, 40, idx - 214720);
        else if (idx < 226920)  cvtw_bd(Wp2, wtp2bd, 33, 132, 66, 80, 40, idx - 216040);
        else if (idx < 244872)  cvtw1(Wp3, wtp3, 132, 132, 136, idx - 226920);
    } else if (b < nb1 + NBLK + nb2 + nb3) {
        int unit = (b - nb1 - NBLK - nb2) * 4 + (tid >> 6);
        int lane = tid & 63;
        if (unit < 320)        prep1(W1, as1, ad1, wt1, 78, 156, 78, 80, 2, unit, lane);
        else if (unit < 960)   prep1f(W2, as2, ad2, va2f, 156, 312, 156, 160, 2, unit - 320, lane);
        else if (unit < 1600)  prep1(W3, as3, ad3, wt3, 312, 312, 312, 320, 1, unit - 960, lane);
        else if (unit < 1760)  prep1f(Wp2, aps2, apd2, vap2f, 33, 132, 66, 40, 2, unit - 1600, lane);
        else if (unit < 2032)  prep1(Wp3, aps3, apd3, wtp3, 132, 132, 132, 136, 1, unit - 1760, lane);
    } else {
        long long i0 = (long long)(b - nb1 - NBLK - nb2 - nb3) * 1024 + tid;
#pragma unroll
        for (int k = 0; k < 4; k++) {
            long long idx = i0 + k * 256;
            if (idx < totM) {
                int n = (int)(idx / 80);
                int kk = (int)(idx - (long long)n * 80);
                xb[idx] = (kk < 78) ? f2bf(mol_x[(long long)n * 78 + kk]) : (unsigned short)0;
            } else if (idx < totM + totP) {
                long long i2 = idx - totM;
                int n = (int)(i2 / 40);
                int kk = (int)(i2 - (long long)n * 40);
                xpp[i2] = (kk < 33) ? f2bf(pro_x[(long long)n * 33 + kk]) : (unsigned short)0;
            }
        }
    }
}

// ==================== scans ====================

__global__ __launch_bounds__(256) void k_scan1(const int* __restrict__ cnt, int* __restrict__ incl,
                                               int* __restrict__ bsums, int n) {
    __shared__ int sm[256];
    int i = blockIdx.x * 256 + threadIdx.x;
    int v = (i < n) ? cnt[i] : 0;
    sm[threadIdx.x] = v;
    __syncthreads();
    for (int off = 1; off < 256; off <<= 1) {
        int t = (threadIdx.x >= off) ? sm[threadIdx.x - off] : 0;
        __syncthreads();
        sm[threadIdx.x] += t;
        __syncthreads();
    }
    if (i < n) incl[i] = sm[threadIdx.x];
    if (threadIdx.x == 255) bsums[blockIdx.x] = sm[255];
}

__global__ __launch_bounds__(1024) void k_scan2(int* __restrict__ bsums, int nb) {
    __shared__ int sm[1024];
    int v = (threadIdx.x < nb) ? bsums[threadIdx.x] : 0;
    sm[threadIdx.x] = v;
    __syncthreads();
    for (int off = 1; off < 1024; off <<= 1) {
        int t = (threadIdx.x >= off) ? sm[threadIdx.x - off] : 0;
        __syncthreads();
        sm[threadIdx.x] += t;
        __syncthreads();
    }
    if (threadIdx.x < nb) bsums[threadIdx.x] = sm[threadIdx.x] - v;
}

__global__ __launch_bounds__(256) void k_scan3_all(const int* __restrict__ incl, const int* __restrict__ cnt,
                                                   const int* __restrict__ boff,
                                                   int* __restrict__ mol_rowp, int* __restrict__ pro_rowp,
                                                   int* __restrict__ cur,
                                                   int N_MOL, int N_PRO, int E_MOL, int E_PRO) {
    int i = blockIdx.x * 256 + threadIdx.x;
    int NT = N_MOL + N_PRO;
    if (i < NT) {
        int ex = incl[i] - cnt[i] + boff[blockIdx.x];
        cur[i] = ex;
        if (i < N_MOL) mol_rowp[i] = ex;
        else pro_rowp[i - N_MOL] = ex - E_MOL;
    }
    if (i == 0) {
        mol_rowp[N_MOL] = E_MOL;
        pro_rowp[N_PRO] = E_PRO;
    }
}

// ==================== bucket-offset scan: hist -> blockstart (in place) ====================
// blockstart[b][blk] = rowp[b<<SH] + exclusive-prefix of hist[b][0..blk)

__global__ __launch_bounds__(256) void k_histscan(int* __restrict__ hist, const int* __restrict__ cur,
                                                  int NBLK, int SH, int NT, int ET) {
    __shared__ int sm[256];
    int b = blockIdx.x;  // bucket
    int t = threadIdx.x;
    int v = (t < NBLK) ? hist[b * NBLK + t] : 0;
    sm[t] = v;
    __syncthreads();
    for (int off = 1; off < 256; off <<= 1) {
        int x = (t >= off) ? sm[t - off] : 0;
        __syncthreads();
        sm[t] += x;
        __syncthreads();
    }
    int node = b << SH;
    int base = (node < NT) ? cur[node] : ET;
    if (t < NBLK) hist[b * NBLK + t] = base + sm[t] - v;  // exclusive
}

// ==================== kernel B: bucket-partition pass1 ∪ GEMM ∪ GEMM ====================
// pass1: each edge-block scatters its edges into bucket-contiguous ebkt runs
// (LDS-atomic per-bucket offsets, write locality ~224B runs vs 64B/edge random).

__global__ __launch_bounds__(256) void k_B(
    const int* __restrict__ msrc, const int* __restrict__ mdst,
    const int* __restrict__ psrc, const int* __restrict__ pdst,
    const float* __restrict__ pw, const int* __restrict__ blockstart, int2* __restrict__ ebkt,
    int N_MOL, int E_MOL, int ET, int nbs, int NBLK, int NBUK, int SH, int ROUNDS,
    const unsigned short* __restrict__ A1, const unsigned short* __restrict__ B1,
    unsigned short* __restrict__ C1, float* __restrict__ as1o, float* __restrict__ ad1o,
    const float* __restrict__ bias1, int relu1, int zpad1,
    int N1, int Kp1, int M1, int Mext1, int Mp1, int H1, int g1x, int nb1,
    const unsigned short* __restrict__ A2, const unsigned short* __restrict__ B2,
    unsigned short* __restrict__ C2, float* __restrict__ as2o, float* __restrict__ ad2o,
    const float* __restrict__ bias2, int relu2, int zpad2,
    int N2, int Kp2, int M2, int Mext2, int Mp2, int H2, int g2x) {
    int b = blockIdx.x;
    if (b < nbs) {
        __shared__ int lofs[256];
        int eb = b;
        int tid = threadIdx.x;
        if (tid < NBUK) lofs[tid] = blockstart[tid * NBLK + eb];
        __syncthreads();
        int base = eb * (ROUNDS * 256);
        for (int r = 0; r < ROUNDS; r++) {
            int e = base + r * 256 + tid;
            if (e < ET) {
                int s, d;
                int wbits = 0;
                if (e >= E_MOL) {
                    int ep = e - E_MOL;
                    s = psrc[ep];
                    d = N_MOL + pdst[ep];
                    wbits = __float_as_int(pw[ep]);
                } else {
                    s = msrc[e];
                    d = mdst[e];
                }
                int bk = d >> SH;
                int pos = atomicAdd(&lofs[bk], 1);
                int2 pk;
                pk.x = s | ((d - (bk << SH)) << 18);  // src (18b) | dst-low (SH b)
                pk.y = wbits;
                ebkt[pos] = pk;
            }
        }
    } else if (b < nbs + nb1) {
        int bb = b - nbs;
        gemm_body(A1, B1, C1, as1o, ad1o, bias1, relu1, zpad1, N1, Kp1, M1, Mext1, Mp1, H1, bb % g1x, bb / g1x);
    } else {
        int bb = b - nbs - nb1;
        gemm_body(A2, B2, C2, as2o, ad2o, bias2, relu2, zpad2, N2, Kp2, M2, Mext2, Mp2, H2, bb % g2x, bb / g2x);
    }
}

// ==================== pass2: bucket-ordered ebkt -> final cpack (bucket-local writes) ====================

__global__ __launch_bounds__(256) void k_pass2(const int2* __restrict__ ebkt, const int* __restrict__ blockstart,
                                               int* __restrict__ cur, int2* __restrict__ cpack,
                                               int NBUK, int NBLK, int SH, int ET) {
    int b = blockIdx.x >> 3;
    int s = blockIdx.x & 7;
    int start = blockstart[b * NBLK];
    int end = (b + 1 < NBUK) ? blockstart[(b + 1) * NBLK] : ET;
    for (int i = start + s * 256 + threadIdx.x; i < end; i += 8 * 256) {
        int2 pk = ebkt[i];
        int src = pk.x & 0x3FFFF;
        int d = (b << SH) | ((unsigned)pk.x >> 18);
        int pos = atomicAdd(&cur[d], 1);
        int2 o;
        o.x = src;
        o.y = pk.y;
        cpack[pos] = o;
    }
}

// ==================== deg/dinv ====================

__global__ __launch_bounds__(256) void k_deg(const int* __restrict__ rowp, const int2* __restrict__ cpack,
                                             float* __restrict__ dinv, int N) {
    int n = blockIdx.x * 256 + threadIdx.x;
    if (n < N) {
        int b = rowp[n], e = rowp[n + 1];
        float s = 0.f;
        for (int p = b; p < e; p++) s += __int_as_float(cpack[p].y);
        dinv[n] = rsqrtf(s + 1.0f);
    }
}

// ==================== fused dispatches ====================

__global__ __launch_bounds__(NPB * 64) void k_fuse1(
    const unsigned short* __restrict__ hb, const float* __restrict__ asm_, const float* __restrict__ adm_,
    const int* __restrict__ mrowp, const int2* __restrict__ mcp, const float* __restrict__ b1,
    unsigned short* __restrict__ x2m, const float* __restrict__ va2f,
    float* __restrict__ asm2, float* __restrict__ adm2, int Nm,
    const unsigned short* __restrict__ hbp, const float* __restrict__ dinv,
    const int* __restrict__ prowp, const int2* __restrict__ pcp, const float* __restrict__ bp1,
    unsigned short* __restrict__ x2p, const float* __restrict__ vap2f,
    float* __restrict__ asp2, float* __restrict__ adp2, int Np, int nb1) {
    int wave = threadIdx.x >> 6, lane = threadIdx.x & 63;
    int b = blockIdx.x;
    if (b < nb1) {
        int nbase = (b * NPB + wave) * 3;
        agg_gp<20, 3, 2, true, 1, false, true>(hb, asm_, adm_, nullptr, mrowp, mcp, b1,
                                               nullptr, x2m, va2f, 160, asm2, adm2,
                                               156, 160, 1, nbase, lane, Nm);
    } else {
        int nbase = ((b - nb1) * NPB + wave) * 12;
        agg_gp<5, 12, 1, false, 1, true, true>(hbp, nullptr, nullptr, dinv, prowp, pcp, bp1,
                                               nullptr, x2p, vap2f, 40, asp2, adp2,
                                               33, 40, 1, nbase, lane, Np);
    }
}

__global__ __launch_bounds__(NPB * 64) void k_fuseN(
    const unsigned short* __restrict__ x2m, const float* __restrict__ asm2, const float* __restrict__ adm2,
    const int* __restrict__ mrowp, const int2* __restrict__ mcp, unsigned short* __restrict__ xa2m, int Nm,
    const unsigned short* __restrict__ x2p, const float* __restrict__ asp2, const float* __restrict__ adp2,
    const int* __restrict__ prowp, const int2* __restrict__ pcp, unsigned short* __restrict__ xa2p, int Np,
    int nb1) {
    int wave = threadIdx.x >> 6, lane = threadIdx.x & 63;
    int b = blockIdx.x;
    if (b < nb1) {
        int nbase = (b * NPB + wave) * 3;
        aggN_gp<20, 3>(x2m, asm2, adm2, mrowp, mcp, xa2m, nbase, lane, Nm);
    } else {
        int nbase = ((b - nb1) * NPB + wave) * 12;
        aggN_gp<5, 12>(x2p, asp2, adp2, prowp, pcp, xa2p, nbase, lane, Np);
    }
}

__global__ __launch_bounds__(NPB * 64) void k_fuse5(
    const unsigned short* __restrict__ hb, const float* __restrict__ asm_, const float* __restrict__ adm_,
    const int* __restrict__ mrowp, const int2* __restrict__ mcp, const float* __restrict__ b3,
    float* __restrict__ out_mol, int Nm,
    const unsigned short* __restrict__ hbp, const float* __restrict__ asp_, const float* __restrict__ adp_,
    const int* __restrict__ prowp, const int2* __restrict__ pcp, const float* __restrict__ bp3,
    float* __restrict__ out_pro, int Np, int nb1) {
    int wave = threadIdx.x >> 6, lane = threadIdx.x & 63;
    int b = blockIdx.x;
    if (b < nb1) {
        int nbase = (b * NPB + wave) * 3;
        agg_gp<20, 3, 1, true, 2, false, false>(hb, asm_, adm_, nullptr, mrowp, mcp, b3,
                                                out_mol, nullptr, nullptr, 0, nullptr, nullptr,
                                                312, 320, 0, nbase, lane, Nm);
    } else {
        int nbase = ((b - nb1) * NPB + wave) * 3;
        agg_gp<17, 3, 1, true, 1, false, false>(hbp, asp_, adp_, nullptr, prowp, pcp, bp3,
                                                out_pro, nullptr, nullptr, 0, nullptr, nullptr,
                                                132, 136, 1, nbase, lane, Np);
    }
}

// ==================== launch ====================

extern "C" void kernel_launch(void* const* d_in, const int* in_sizes, int n_in,
                              void* d_out, int out_size, void* d_ws, size_t ws_size,
                              hipStream_t stream) {
    const int N_MOL = in_sizes[0] / 78;
    const int E_MOL = in_sizes[1] / 2;
    const int N_PRO = in_sizes[2] / 33;
    const int E_PRO = in_sizes[3] / 2;
    const int NT = N_MOL + N_PRO;
    const int ET = E_MOL + E_PRO;

    const float* mol_x = (const float*)d_in[0];
    const int* mol_ei = (const int*)d_in[1];
    const float* pro_x = (const float*)d_in[2];
    const int* pro_ei = (const int*)d_in[3];
    const float* pro_ew = (const float*)d_in[4];
    const float *W1 = (const float*)d_in[5], *as1 = (const float*)d_in[6], *ad1 = (const float*)d_in[7],
                *b1 = (const float*)d_in[8];
    const float *W2 = (const float*)d_in[9], *as2 = (const float*)d_in[10], *ad2 = (const float*)d_in[11],
                *b2 = (const float*)d_in[12];
    const float *W3 = (const float*)d_in[13], *as3 = (const float*)d_in[14], *ad3 = (const float*)d_in[15],
                *b3 = (const float*)d_in[16];
    const float *Wp1 = (const float*)d_in[17], *bp1 = (const float*)d_in[18];
    const float *Wp2 = (const float*)d_in[19], *aps2 = (const float*)d_in[20], *apd2 = (const float*)d_in[21],
                *bp2 = (const float*)d_in[22];
    const float *Wp3 = (const float*)d_in[23], *aps3 = (const float*)d_in[24], *apd3 = (const float*)d_in[25],
                *bp3 = (const float*)d_in[26];

    float* out_mol = (float*)d_out;
    float* out_pro = (float*)d_out + (size_t)N_MOL * 312;

    // bucket-partition parameters
    int SH = 10;
    while (((NT + (1 << SH) - 1) >> SH) > 256) SH++;
    const int NBUK = (NT + (1 << SH) - 1) >> SH;          // <= 256
    int ROUNDS = (ET + 65535) / 65536;                     // edges per block = ROUNDS*256
    if (ROUNDS < 16) ROUNDS = 16;
    const int EB = ROUNDS * 256;
    const int NBLK = (ET + EB - 1) / EB;                   // <= 256

    // ---------- d_out as scratch for buffers dead before F5 (passed in R7/R8) ----------
    char* ob = (char*)d_out;
    size_t o_xa2m = 0;
    size_t o_xa2p = o_xa2m + (size_t)N_MOL * 320 * 2;
    size_t o_xb0  = o_xa2p + (size_t)N_PRO * 80 * 2;
    size_t o_xp0  = o_xb0 + (size_t)N_MOL * 80 * 2;
    size_t o_xpp  = o_xp0 + (size_t)N_PRO * 40 * 2;
    unsigned short* xa2m = (unsigned short*)(ob + o_xa2m);
    unsigned short* xa2p = (unsigned short*)(ob + o_xa2p);
    unsigned short* xb0  = (unsigned short*)(ob + o_xb0);
    unsigned short* xp0  = (unsigned short*)(ob + o_xp0);
    unsigned short* xpp  = (unsigned short*)(ob + o_xpp);

    // ---------- workspace (~115 MB; R5's proven-good footprint was 131 MB) ----------
    char* p = (char*)d_ws;
    auto alloc = [&](size_t bytes) -> void* {
        void* r = (void*)p;
        p += (bytes + 255) & ~(size_t)255;
        return r;
    };
    int* cnt_all  = (int*)alloc((size_t)NT * 4);
    int* incl     = (int*)alloc((size_t)NT * 4);
    int* cur_all  = (int*)alloc((size_t)NT * 4);
    int* bsums    = (int*)alloc(1024 * 4);
    int* mol_rowp = (int*)alloc((size_t)(N_MOL + 1) * 4);
    int* pro_rowp = (int*)alloc((size_t)(N_PRO + 1) * 4);
    int2* cpack   = (int2*)alloc((size_t)ET * 8);
    int2* ebkt    = (int2*)alloc((size_t)ET * 8);
    int* hist     = (int*)alloc((size_t)256 * 256 * 4);    // NBUK*NBLK <= 256*256
    float* dinv   = (float*)alloc((size_t)N_PRO * 4);
    float* asb_m  = (float*)alloc((size_t)N_MOL * 2 * 4);
    float* adb_m  = (float*)alloc((size_t)N_MOL * 2 * 4);
    float* asb_m2 = (float*)alloc((size_t)N_MOL * 2 * 4);
    float* adb_m2 = (float*)alloc((size_t)N_MOL * 2 * 4);
    float* asb_p  = (float*)alloc((size_t)N_PRO * 2 * 4);
    float* adb_p  = (float*)alloc((size_t)N_PRO * 2 * 4);
    float* asb_p2 = (float*)alloc((size_t)N_PRO * 2 * 4);
    float* adb_p2 = (float*)alloc((size_t)N_PRO * 2 * 4);
    float* va2f   = (float*)alloc((size_t)4 * 160 * 4);
    float* vap2f  = (float*)alloc((size_t)4 * 40 * 4);
    unsigned short* bufA = (unsigned short*)alloc((size_t)N_MOL * 320 * 2);
    unsigned short* bufB = (unsigned short*)alloc((size_t)N_MOL * 320 * 2);
    unsigned short* bufC = (unsigned short*)alloc((size_t)N_PRO * 136 * 2);
    unsigned short* wt1    = (unsigned short*)alloc((size_t)160 * 80 * 2);
    unsigned short* wt2bd  = (unsigned short*)alloc((size_t)320 * 320 * 2);
    unsigned short* wt3    = (unsigned short*)alloc((size_t)320 * 320 * 2);
    unsigned short* wtp1   = (unsigned short*)alloc((size_t)40 * 40 * 2);
    unsigned short* wtp2bd = (unsigned short*)alloc((size_t)136 * 80 * 2);
    unsigned short* wtp3   = (unsigned short*)alloc((size_t)136 * 136 * 2);
    (void)ws_size;

    unsigned short* hb1  = bufA;
    unsigned short* x3m  = bufA;
    unsigned short* x2m  = bufB;
    unsigned short* x2p  = bufB + (size_t)N_MOL * 160;
    unsigned short* hb3  = bufB;
    unsigned short* hbp1 = bufC;
    unsigned short* hbp3 = bufC;

    int2* mol_cp = cpack;
    int2* pro_cp = cpack + E_MOL;

    const int* mol_src = mol_ei;
    const int* mol_dst = mol_ei + E_MOL;
    const int* pro_src = pro_ei;
    const int* pro_dst = pro_ei + E_PRO;

    const long long totM = (long long)N_MOL * 80;
    const long long totP = (long long)N_PRO * 40;

    // ---- A: count ∪ bucket-hist ∪ cvt_w ∪ prep_va ∪ cvt_x ----
    hipMemsetAsync(cnt_all, 0, (size_t)NT * 4, stream);
    int nbCnt = (ET + 1023) / 1024;
    int nbCvx = (int)((totM + totP + 1023) / 1024);
    int gridA = nbCnt + NBLK + 957 + 508 + nbCvx;
    k_A<<<gridA, 256, 0, stream>>>(mol_dst, pro_dst, cnt_all, N_MOL, E_MOL, ET, nbCnt,
                                   hist, NBLK, NBUK, SH, ROUNDS,
                                   W1, W2, W3, Wp1, Wp2, Wp3, wt1, wt2bd, wt3, wtp1, wtp2bd, wtp3,
                                   as1, ad1, as2, ad2, as3, ad3, aps2, apd2, aps3, apd3,
                                   va2f, vap2f, mol_x, xb0, pro_x, xp0, totM, totP);

    // ---- scans ----
    int nbT = (NT + 255) / 256;
    k_scan1<<<nbT, 256, 0, stream>>>(cnt_all, incl, bsums, NT);
    k_scan2<<<1, 1024, 0, stream>>>(bsums, nbT);
    k_scan3_all<<<nbT, 256, 0, stream>>>(incl, cnt_all, bsums, mol_rowp, pro_rowp, cur_all,
                                         N_MOL, N_PRO, E_MOL, E_PRO);

    // ---- bucket-offset scan (hist -> blockstart, in place) ----
    k_histscan<<<NBUK, 256, 0, stream>>>(hist, cur_all, NBLK, SH, NT, ET);

    int gyM = (N_MOL + TBM - 1) / TBM;
    int gyP = (N_PRO + TBM - 1) / TBM;

    // ---- B1: bucket-partition pass1 ∪ GEMM1m (alpha rows) ∪ GEMMp1 (plain) ----
    {
        int g1x = 2;                       // Mext=160
        int nb1 = g1x * gyM;
        int g2x = 1;                       // Mext=33
        k_B<<<NBLK + nb1 + g2x * gyP, 256, 0, stream>>>(
            mol_src, mol_dst, pro_src, pro_dst, pro_ew, hist, ebkt,
            N_MOL, E_MOL, ET, NBLK, NBLK, NBUK, SH, ROUNDS,
            xb0, wt1, hb1, asb_m, adb_m, nullptr, 0, 0, N_MOL, 80, 156, 160, 160, 2, g1x, nb1,
            xp0, wtp1, hbp1, nullptr, nullptr, nullptr, 0, 0, N_PRO, 40, 33, 33, 40, 0, g2x);
    }

    // ---- pass2: ebkt -> cpack (bucket-local final scatter) ----
    k_pass2<<<NBUK * 8, 256, 0, stream>>>(ebkt, hist, cur_all, cpack, NBUK, NBLK, SH, ET);

    k_deg<<<(N_PRO + 255) / 256, 256, 0, stream>>>(pro_rowp, pro_cp, dinv, N_PRO);

    // ---- F1: agg1m (->x2m, as2) ∪ gcn agg (->x2p, asp2) ----
    {
        int nb1 = (N_MOL + NPB * 3 - 1) / (NPB * 3);
        int nb2 = (N_PRO + NPB * 12 - 1) / (NPB * 12);
        k_fuse1<<<nb1 + nb2, NPB * 64, 0, stream>>>(hb1, asb_m, adb_m, mol_rowp, mol_cp, b1,
                                                    x2m, va2f, asb_m2, adb_m2, N_MOL,
                                                    hbp1, dinv, pro_rowp, pro_cp, bp1,
                                                    x2p, vap2f, asb_p2, adb_p2, N_PRO, nb1);
    }

    // ---- F2: input-space aggs (x2m -> xa2m) ∪ (x2p -> xa2p) ----
    {
        int nb1 = (N_MOL + NPB * 3 - 1) / (NPB * 3);
        int nb2 = (N_PRO + NPB * 12 - 1) / (NPB * 12);
        k_fuseN<<<nb1 + nb2, NPB * 64, 0, stream>>>(x2m, asb_m2, adb_m2, mol_rowp, mol_cp, xa2m, N_MOL,
                                                    x2p, asb_p2, adb_p2, pro_rowp, pro_cp, xa2p, N_PRO, nb1);
    }

    // ---- F3: block-diag GEMMs ----
    {
        int g1x = 3;                       // Mext=320
        int nb1 = g1x * gyM;
        int g2x = 2;                       // Mext=136
        k_B<<<nb1 + g2x * gyP, 256, 0, stream>>>(
            nullptr, nullptr, nullptr, nullptr, nullptr, nullptr, nullptr,
            N_MOL, E_MOL, ET, 0, NBLK, NBUK, SH, ROUNDS,
            xa2m, wt2bd, x3m, nullptr, nullptr, b2, 1, 320, N_MOL, 320, 312, 320, 320, 0, g1x, nb1,
            xa2p, wtp2bd, xpp, nullptr, nullptr, bp2, 1, 136, N_PRO, 80, 132, 136, 136, 0, g2x);
    }

    // ---- F4: GEMM3m (alpha) ∪ GEMMp3 (alpha) ----
    {
        int g1x = 3;                       // Mext=314
        int nb1 = g1x * gyM;
        int g2x = 2;                       // Mext=134
        k_B<<<nb1 + g2x * gyP, 256, 0, stream>>>(
            nullptr, nullptr, nullptr, nullptr, nullptr, nullptr, nullptr,
            N_MOL, E_MOL, ET, 0, NBLK, NBUK, SH, ROUNDS,
            x3m, wt3, hb3, asb_m, adb_m, nullptr, 0, 0, N_MOL, 320, 312, 314, 320, 1, g1x, nb1,
            xpp, wtp3, hbp3, asb_p, adb_p, nullptr, 0, 0, N_PRO, 136, 132, 134, 136, 1, g2x);
    }

    // ---- F5: final aggs -> outputs ----
    {
        int nb1 = (N_MOL + NPB * 3 - 1) / (NPB * 3);
        int nb2 = (N_PRO + NPB * 3 - 1) / (NPB * 3);
        k_fuse5<<<nb1 + nb2, NPB * 64, 0, stream>>>(hb3, asb_m, adb_m, mol_rowp, mol_cp, b3, out_mol, N_MOL,
                                                    hbp3, asb_p, adb_p, pro_rowp, pro_cp, bp3, out_pro, N_PRO, nb1);
    }
}